// Round 1
// baseline (776.544 us; speedup 1.0000x reference)
//
#include <hip/hip_runtime.h>

#define D_DIM 128
#define ROWS 32        // fp32 fallback tile
#define MROWS 64       // mfma kernel rows per block
#define ZPAD 136       // bf16 elems per LDS row: 272 B = 16B-aligned, low bank conflict

typedef __bf16 bf16x8 __attribute__((ext_vector_type(8)));
typedef __bf16 bf16x4 __attribute__((ext_vector_type(4)));
typedef float  f32x4  __attribute__((ext_vector_type(4)));

// ---------------------------------------------------------------------------
// Fallback SpMM (atomic): side[dst] += val * x[src]
// ---------------------------------------------------------------------------
__global__ __launch_bounds__(256) void spmm_atomic(
    const float* __restrict__ x, const int* __restrict__ src,
    const int* __restrict__ dst, const float* __restrict__ val,
    float* __restrict__ side, long long total)
{
    long long i = (long long)blockIdx.x * blockDim.x + threadIdx.x;
    if (i >= total) return;
    int e = (int)(i >> 5);
    int q = (int)(i & 31);
    int s = src[e];
    int d = dst[e];
    float v = val[e];
    const float4 xv = *reinterpret_cast<const float4*>(x + (long long)s * D_DIM + q * 4);
    float* o = side + (long long)d * D_DIM + q * 4;
    unsafeAtomicAdd(o + 0, v * xv.x);
    unsafeAtomicAdd(o + 1, v * xv.y);
    unsafeAtomicAdd(o + 2, v * xv.z);
    unsafeAtomicAdd(o + 3, v * xv.w);
}

// ---------------------------------------------------------------------------
// CSR build: histogram -> exclusive scan -> scatter
// ---------------------------------------------------------------------------
__global__ __launch_bounds__(256) void hist_kernel(
    const int* __restrict__ dst, int* __restrict__ cnt, int E)
{
    int i = blockIdx.x * 256 + threadIdx.x;
    if (i < E) atomicAdd(&cnt[dst[i]], 1);
}

__global__ __launch_bounds__(256) void scan_blocks(
    const int* __restrict__ cnt, int* __restrict__ row_ptr,
    int* __restrict__ blk_sums, int N)
{
    __shared__ int sh[256];
    int i = blockIdx.x * 256 + threadIdx.x;
    int v = (i < N) ? cnt[i] : 0;
    sh[threadIdx.x] = v;
    __syncthreads();
#pragma unroll
    for (int off = 1; off < 256; off <<= 1) {
        int t = (threadIdx.x >= off) ? sh[threadIdx.x - off] : 0;
        __syncthreads();
        sh[threadIdx.x] += t;
        __syncthreads();
    }
    if (i < N) row_ptr[i] = sh[threadIdx.x] - v;
    if (threadIdx.x == 255) blk_sums[blockIdx.x] = sh[255];
}

__global__ __launch_bounds__(256) void scan_carry(int* __restrict__ blk, int B)
{
    __shared__ int sh[256];
    __shared__ int carry;
    if (threadIdx.x == 0) carry = 0;
    __syncthreads();
    for (int base = 0; base < B; base += 256) {
        int i = base + threadIdx.x;
        int v = (i < B) ? blk[i] : 0;
        sh[threadIdx.x] = v;
        __syncthreads();
#pragma unroll
        for (int off = 1; off < 256; off <<= 1) {
            int t = (threadIdx.x >= off) ? sh[threadIdx.x - off] : 0;
            __syncthreads();
            sh[threadIdx.x] += t;
            __syncthreads();
        }
        int excl = sh[threadIdx.x] - v + carry;
        if (i < B) blk[i] = excl;
        __syncthreads();
        if (threadIdx.x == 255) carry = carry + sh[255];
        __syncthreads();
    }
}

__global__ __launch_bounds__(256) void scan_add(
    int* __restrict__ row_ptr, const int* __restrict__ blk_sums,
    int* __restrict__ row_fill, int N, int E)
{
    int i = blockIdx.x * 256 + threadIdx.x;
    if (i < N) {
        int v = row_ptr[i] + blk_sums[i >> 8];
        row_ptr[i]  = v;
        row_fill[i] = v;
    }
    if (i == 0) row_ptr[N] = E;
}

// Interleaved (src, val-as-int) pairs: one 8B random store per edge instead of
// two 4B stores to different arrays (halves scatter line traffic), and one 8B
// load per edge in the SpMM.
__global__ __launch_bounds__(256) void scatter_kernel(
    const int* __restrict__ src, const int* __restrict__ dst,
    const float* __restrict__ val, int* __restrict__ row_fill,
    int2* __restrict__ csr_sv, int E)
{
    int e = blockIdx.x * 256 + threadIdx.x;
    if (e >= E) return;
    int d = dst[e];
    int pos = atomicAdd(&row_fill[d], 1);
    csr_sv[pos] = make_int2(src[e], __float_as_int(val[e]));
}

// ---------------------------------------------------------------------------
// W^T bf16 precompute: WT[l][n][k] = bf16(W[l][k][n]), both matrices.
// ---------------------------------------------------------------------------
__global__ __launch_bounds__(256) void wt_convert(
    const float* __restrict__ Wsum, const float* __restrict__ Wprod,
    __bf16* __restrict__ WTsum, __bf16* __restrict__ WTprod, int total)
{
    int i = blockIdx.x * 256 + threadIdx.x;
    if (i >= total) return;
    int l  = i >> 14;
    int nk = i & 16383;
    int n  = nk >> 7;
    int k  = nk & 127;
    int widx = (l << 14) + (k << 7) + n;
    WTsum[i]  = (__bf16)Wsum[widx];
    WTprod[i] = (__bf16)Wprod[widx];
}

// ---------------------------------------------------------------------------
// CSR SpMM: one 32-lane group per dst row.
// 8-deep edge unroll, all gathers issued before any FMA -> 8 float4 loads in
// flight per half-wave (prev version compiled to VGPR=24 => serialized chain).
// ---------------------------------------------------------------------------
__global__ __launch_bounds__(256) void spmm_csr(
    const float* __restrict__ x, const int* __restrict__ row_ptr,
    const int2* __restrict__ csr_sv, float* __restrict__ side, int N)
{
    int row  = blockIdx.x * 8 + (threadIdx.x >> 5);
    int lane = threadIdx.x & 31;
    if (row >= N) return;
    int start = row_ptr[row];
    int end   = row_ptr[row + 1];
    const float* xl = x + lane * 4;
    float4 acc = make_float4(0.f, 0.f, 0.f, 0.f);
    int j = start;
    for (; j + 8 <= end; j += 8) {
        int2 sv0 = csr_sv[j + 0], sv1 = csr_sv[j + 1];
        int2 sv2 = csr_sv[j + 2], sv3 = csr_sv[j + 3];
        int2 sv4 = csr_sv[j + 4], sv5 = csr_sv[j + 5];
        int2 sv6 = csr_sv[j + 6], sv7 = csr_sv[j + 7];
        const float4 x0 = *reinterpret_cast<const float4*>(xl + (long long)sv0.x * D_DIM);
        const float4 x1 = *reinterpret_cast<const float4*>(xl + (long long)sv1.x * D_DIM);
        const float4 x2 = *reinterpret_cast<const float4*>(xl + (long long)sv2.x * D_DIM);
        const float4 x3 = *reinterpret_cast<const float4*>(xl + (long long)sv3.x * D_DIM);
        const float4 x4 = *reinterpret_cast<const float4*>(xl + (long long)sv4.x * D_DIM);
        const float4 x5 = *reinterpret_cast<const float4*>(xl + (long long)sv5.x * D_DIM);
        const float4 x6 = *reinterpret_cast<const float4*>(xl + (long long)sv6.x * D_DIM);
        const float4 x7 = *reinterpret_cast<const float4*>(xl + (long long)sv7.x * D_DIM);
        float v0 = __int_as_float(sv0.y), v1 = __int_as_float(sv1.y);
        float v2 = __int_as_float(sv2.y), v3 = __int_as_float(sv3.y);
        float v4 = __int_as_float(sv4.y), v5 = __int_as_float(sv5.y);
        float v6 = __int_as_float(sv6.y), v7 = __int_as_float(sv7.y);
        acc.x += v0 * x0.x + v1 * x1.x + v2 * x2.x + v3 * x3.x;
        acc.y += v0 * x0.y + v1 * x1.y + v2 * x2.y + v3 * x3.y;
        acc.z += v0 * x0.z + v1 * x1.z + v2 * x2.z + v3 * x3.z;
        acc.w += v0 * x0.w + v1 * x1.w + v2 * x2.w + v3 * x3.w;
        acc.x += v4 * x4.x + v5 * x5.x + v6 * x6.x + v7 * x7.x;
        acc.y += v4 * x4.y + v5 * x5.y + v6 * x6.y + v7 * x7.y;
        acc.z += v4 * x4.z + v5 * x5.z + v6 * x6.z + v7 * x7.z;
        acc.w += v4 * x4.w + v5 * x5.w + v6 * x6.w + v7 * x7.w;
    }
    for (; j + 4 <= end; j += 4) {
        int2 sv0 = csr_sv[j + 0], sv1 = csr_sv[j + 1];
        int2 sv2 = csr_sv[j + 2], sv3 = csr_sv[j + 3];
        const float4 x0 = *reinterpret_cast<const float4*>(xl + (long long)sv0.x * D_DIM);
        const float4 x1 = *reinterpret_cast<const float4*>(xl + (long long)sv1.x * D_DIM);
        const float4 x2 = *reinterpret_cast<const float4*>(xl + (long long)sv2.x * D_DIM);
        const float4 x3 = *reinterpret_cast<const float4*>(xl + (long long)sv3.x * D_DIM);
        float v0 = __int_as_float(sv0.y), v1 = __int_as_float(sv1.y);
        float v2 = __int_as_float(sv2.y), v3 = __int_as_float(sv3.y);
        acc.x += v0 * x0.x + v1 * x1.x + v2 * x2.x + v3 * x3.x;
        acc.y += v0 * x0.y + v1 * x1.y + v2 * x2.y + v3 * x3.y;
        acc.z += v0 * x0.z + v1 * x1.z + v2 * x2.z + v3 * x3.z;
        acc.w += v0 * x0.w + v1 * x1.w + v2 * x2.w + v3 * x3.w;
    }
    for (; j < end; ++j) {
        int2 sv = csr_sv[j];
        float v = __int_as_float(sv.y);
        const float4 xv = *reinterpret_cast<const float4*>(xl + (long long)sv.x * D_DIM);
        acc.x += v * xv.x;
        acc.y += v * xv.y;
        acc.z += v * xv.z;
        acc.w += v * xv.w;
    }
    *reinterpret_cast<float4*>(side + (long long)row * D_DIM + lane * 4) = acc;
}

// ---------------------------------------------------------------------------
// MFMA fused BiAggregator layer.
//   Block: 256 thr = 4 waves; 64 rows x 128 cols. Wave w: rows w*16..w*16+15.
//   z=ego+side, m=ego*side staged as bf16 in LDS (full K=128, one barrier).
//   B-frags read from pre-transposed bf16 WT (global, L2-resident).
//   mfma_f32_16x16x32_bf16: A[m=lane&15][k=quad*8+j]; D: col=lane&15,
//   row=quad*4+reg (m89/m120-verified layouts).
// ---------------------------------------------------------------------------
__global__ __launch_bounds__(256) void fused_layer_mfma(
    const float* __restrict__ ego, const float* __restrict__ side,
    const __bf16* __restrict__ WTsum, const float* __restrict__ bsum,
    const __bf16* __restrict__ WTprod, const float* __restrict__ bprod,
    float* __restrict__ ego_out,   // may be nullptr (last layer)
    float* __restrict__ norm_out, int N)
{
    __shared__ __bf16 zt[MROWS][ZPAD];
    __shared__ __bf16 mt[MROWS][ZPAD];

    const int tid  = threadIdx.x;
    const int row0 = blockIdx.x * MROWS;

    // ---- stage z, m as bf16 (each thread 8 float4-pairs) ----
    for (int idx = tid; idx < MROWS * 32; idx += 256) {
        int r = idx >> 5, q = idx & 31;
        int row = row0 + r;
        float4 e4 = make_float4(0.f, 0.f, 0.f, 0.f);
        float4 s4 = make_float4(0.f, 0.f, 0.f, 0.f);
        if (row < N) {
            e4 = *reinterpret_cast<const float4*>(ego  + (long long)row * D_DIM + q * 4);
            s4 = *reinterpret_cast<const float4*>(side + (long long)row * D_DIM + q * 4);
        }
        bf16x4 z4, m4;
        z4[0] = (__bf16)(e4.x + s4.x); z4[1] = (__bf16)(e4.y + s4.y);
        z4[2] = (__bf16)(e4.z + s4.z); z4[3] = (__bf16)(e4.w + s4.w);
        m4[0] = (__bf16)(e4.x * s4.x); m4[1] = (__bf16)(e4.y * s4.y);
        m4[2] = (__bf16)(e4.z * s4.z); m4[3] = (__bf16)(e4.w * s4.w);
        *reinterpret_cast<bf16x4*>(&zt[r][q * 4]) = z4;
        *reinterpret_cast<bf16x4*>(&mt[r][q * 4]) = m4;
    }
    __syncthreads();

    const int wave = tid >> 6;
    const int lane = tid & 63;
    const int ln   = lane & 15;        // n within tile / m within A
    const int quad = lane >> 4;        // k-block selector (A/B), row-block (C)
    const int mloc = wave * 16;        // this wave's row base within block

    f32x4 acc_s[8], acc_p[8];
#pragma unroll
    for (int nt = 0; nt < 8; ++nt) {
        acc_s[nt] = (f32x4){0.f, 0.f, 0.f, 0.f};
        acc_p[nt] = (f32x4){0.f, 0.f, 0.f, 0.f};
    }

#pragma unroll
    for (int ks = 0; ks < 4; ++ks) {
        const int k0 = ks * 32 + quad * 8;
        bf16x8 az = *reinterpret_cast<const bf16x8*>(&zt[mloc + ln][k0]);
        bf16x8 am = *reinterpret_cast<const bf16x8*>(&mt[mloc + ln][k0]);
#pragma unroll
        for (int nt = 0; nt < 8; ++nt) {
            const long long wofs = (long long)(nt * 16 + ln) * D_DIM + k0;
            bf16x8 bs = *reinterpret_cast<const bf16x8*>(WTsum  + wofs);
            bf16x8 bp = *reinterpret_cast<const bf16x8*>(WTprod + wofs);
            acc_s[nt] = __builtin_amdgcn_mfma_f32_16x16x32_bf16(az, bs, acc_s[nt], 0, 0, 0);
            acc_p[nt] = __builtin_amdgcn_mfma_f32_16x16x32_bf16(am, bp, acc_p[nt], 0, 0, 0);
        }
    }

    // ---- epilogue: bias + lrelu + add, row L2-norm, stores ----
    float bsv[8], bpv[8];
#pragma unroll
    for (int nt = 0; nt < 8; ++nt) {
        bsv[nt] = bsum[nt * 16 + ln];
        bpv[nt] = bprod[nt * 16 + ln];
    }
    float part[4] = {0.f, 0.f, 0.f, 0.f};
#pragma unroll
    for (int nt = 0; nt < 8; ++nt) {
#pragma unroll
        for (int r = 0; r < 4; ++r) {
            float sv = acc_s[nt][r] + bsv[nt];
            sv = sv > 0.f ? sv : 0.01f * sv;
            float pv = acc_p[nt][r] + bpv[nt];
            pv = pv > 0.f ? pv : 0.01f * pv;
            float e = sv + pv;
            acc_s[nt][r] = e;           // reuse as e-store
            part[r] += e * e;
        }
    }
#pragma unroll
    for (int off = 1; off < 16; off <<= 1) {
#pragma unroll
        for (int r = 0; r < 4; ++r)
            part[r] += __shfl_xor(part[r], off, 16);
    }
#pragma unroll
    for (int r = 0; r < 4; ++r) {
        int row = row0 + mloc + quad * 4 + r;
        if (row >= N) continue;
        float inv = 1.0f / fmaxf(sqrtf(part[r]), 1e-12f);
        long long base = (long long)row * D_DIM + ln;
#pragma unroll
        for (int nt = 0; nt < 8; ++nt)
            norm_out[base + nt * 16] = acc_s[nt][r] * inv;
        if (ego_out) {
#pragma unroll
            for (int nt = 0; nt < 8; ++nt)
                ego_out[base + nt * 16] = acc_s[nt][r];
        }
    }
}

// ---------------------------------------------------------------------------
// fp32 fallback fused layer (R1 version)
// ---------------------------------------------------------------------------
__global__ __launch_bounds__(256) void fused_layer_f32(
    const float* __restrict__ ego, const float* __restrict__ side,
    const float* __restrict__ Wsum, const float* __restrict__ bsum,
    const float* __restrict__ Wprod, const float* __restrict__ bprod,
    float* __restrict__ ego_out, float* __restrict__ norm_out, int N)
{
    __shared__ float zt[ROWS][D_DIM];
    __shared__ float mt[ROWS][D_DIM];
    __shared__ float wsh[32][D_DIM];
    __shared__ float wph[32][D_DIM];

    const int tid  = threadIdx.x;
    const int row0 = blockIdx.x * ROWS;
    const int cg   = tid & 31;
    const int rg   = tid >> 5;

    for (int idx = tid; idx < ROWS * 32; idx += 256) {
        int r = idx >> 5, q = idx & 31;
        int row = row0 + r;
        float4 e4 = make_float4(0.f, 0.f, 0.f, 0.f);
        float4 s4 = make_float4(0.f, 0.f, 0.f, 0.f);
        if (row < N) {
            e4 = *reinterpret_cast<const float4*>(ego  + (long long)row * D_DIM + q * 4);
            s4 = *reinterpret_cast<const float4*>(side + (long long)row * D_DIM + q * 4);
        }
        float4 z4 = make_float4(e4.x + s4.x, e4.y + s4.y, e4.z + s4.z, e4.w + s4.w);
        float4 m4 = make_float4(e4.x * s4.x, e4.y * s4.y, e4.z * s4.z, e4.w * s4.w);
        *reinterpret_cast<float4*>(&zt[r][q * 4]) = z4;
        *reinterpret_cast<float4*>(&mt[r][q * 4]) = m4;
    }

    float acc_s[4][4], acc_p[4][4];
#pragma unroll
    for (int a = 0; a < 4; ++a)
#pragma unroll
        for (int b = 0; b < 4; ++b) { acc_s[a][b] = 0.f; acc_p[a][b] = 0.f; }

    for (int kc = 0; kc < D_DIM; kc += 32) {
        __syncthreads();
        for (int idx = tid; idx < 32 * 32; idx += 256) {
            int kk = idx >> 5, q = idx & 31;
            *reinterpret_cast<float4*>(&wsh[kk][q * 4]) =
                *reinterpret_cast<const float4*>(Wsum + (long long)(kc + kk) * D_DIM + q * 4);
            *reinterpret_cast<float4*>(&wph[kk][q * 4]) =
                *reinterpret_cast<const float4*>(Wprod + (long long)(kc + kk) * D_DIM + q * 4);
        }
        __syncthreads();
#pragma unroll 8
        for (int kk = 0; kk < 32; ++kk) {
            float4 w_s = *reinterpret_cast<const float4*>(&wsh[kk][cg * 4]);
            float4 w_p = *reinterpret_cast<const float4*>(&wph[kk][cg * 4]);
#pragma unroll
            for (int rr = 0; rr < 4; ++rr) {
                float z = zt[rg * 4 + rr][kc + kk];
                float m = mt[rg * 4 + rr][kc + kk];
                acc_s[rr][0] += z * w_s.x; acc_s[rr][1] += z * w_s.y;
                acc_s[rr][2] += z * w_s.z; acc_s[rr][3] += z * w_s.w;
                acc_p[rr][0] += m * w_p.x; acc_p[rr][1] += m * w_p.y;
                acc_p[rr][2] += m * w_p.z; acc_p[rr][3] += m * w_p.w;
            }
        }
    }

    const float4 bs = *reinterpret_cast<const float4*>(bsum  + cg * 4);
    const float4 bp = *reinterpret_cast<const float4*>(bprod + cg * 4);
    float ev[4][4];
    float part[4];
#pragma unroll
    for (int rr = 0; rr < 4; ++rr) {
        float bsv[4] = {bs.x, bs.y, bs.z, bs.w};
        float bpv[4] = {bp.x, bp.y, bp.z, bp.w};
        float acc = 0.f;
#pragma unroll
        for (int cc = 0; cc < 4; ++cc) {
            float sv = acc_s[rr][cc] + bsv[cc];
            sv = sv > 0.f ? sv : 0.01f * sv;
            float pv = acc_p[rr][cc] + bpv[cc];
            pv = pv > 0.f ? pv : 0.01f * pv;
            float e = sv + pv;
            ev[rr][cc] = e;
            acc += e * e;
        }
        part[rr] = acc;
    }
#pragma unroll
    for (int off = 1; off < 32; off <<= 1) {
#pragma unroll
        for (int rr = 0; rr < 4; ++rr)
            part[rr] += __shfl_xor(part[rr], off, 32);
    }
#pragma unroll
    for (int rr = 0; rr < 4; ++rr) {
        int row = row0 + rg * 4 + rr;
        if (row >= N) continue;
        float inv = 1.0f / fmaxf(sqrtf(part[rr]), 1e-12f);
        float4 o  = make_float4(ev[rr][0] * inv, ev[rr][1] * inv,
                                ev[rr][2] * inv, ev[rr][3] * inv);
        *reinterpret_cast<float4*>(norm_out + (long long)row * D_DIM + cg * 4) = o;
        if (ego_out) {
            float4 g = make_float4(ev[rr][0], ev[rr][1], ev[rr][2], ev[rr][3]);
            *reinterpret_cast<float4*>(ego_out + (long long)row * D_DIM + cg * 4) = g;
        }
    }
}

// ---------------------------------------------------------------------------
extern "C" void kernel_launch(void* const* d_in, const int* in_sizes, int n_in,
                              void* d_out, int out_size, void* d_ws, size_t ws_size,
                              hipStream_t stream)
{
    const float* emb   = (const float*)d_in[0];
    const int*   esrc  = (const int*)  d_in[1];
    const int*   edst  = (const int*)  d_in[2];
    const float* evalv = (const float*)d_in[3];
    const float* Wsum  = (const float*)d_in[4];
    const float* bsum  = (const float*)d_in[5];
    const float* Wprod = (const float*)d_in[6];
    const float* bprod = (const float*)d_in[7];
    float* out = (float*)d_out;

    const int D = 128;
    const int N = in_sizes[0] / D;
    const int E = in_sizes[1];
    const int L = in_sizes[5] / D;
    const size_t ND = (size_t)N * D;
    const int B = (N + 255) / 256;

    // workspace layout
    char* ws = (char*)d_ws;
    float* side    = (float*)ws;                 ws += ND * sizeof(float);
    float* ego_buf = (float*)ws;                 ws += ND * sizeof(float);
    int*   row_ptr  = (int*)ws;                  ws += (size_t)(N + 1) * sizeof(int);
    int*   row_fill = (int*)ws;                  ws += (size_t)N * sizeof(int);
    int*   blk_sums = (int*)ws;                  ws += (size_t)B * sizeof(int);
    ws = (char*)(((uintptr_t)ws + 15) & ~(uintptr_t)15);   // align for int2/vec
    int2*  csr_sv   = (int2*)ws;                 ws += (size_t)E * sizeof(int2);
    size_t csr_bytes = (size_t)(ws - (char*)d_ws);
    __bf16* WTsum  = (__bf16*)ws;                ws += (size_t)L * D * D * sizeof(__bf16);
    __bf16* WTprod = (__bf16*)ws;                ws += (size_t)L * D * D * sizeof(__bf16);
    size_t mfma_bytes = (size_t)(ws - (char*)d_ws);

    const bool use_csr  = (ws_size >= csr_bytes);
    const bool use_mfma = (ws_size >= mfma_bytes);

    // out[0] = embeddings
    hipMemcpyAsync(out, emb, ND * sizeof(float), hipMemcpyDeviceToDevice, stream);

    if (use_csr) {
        hipMemsetAsync(row_fill, 0, (size_t)N * sizeof(int), stream);
        hist_kernel<<<(E + 255) / 256, 256, 0, stream>>>(edst, row_fill, E);
        scan_blocks<<<B, 256, 0, stream>>>(row_fill, row_ptr, blk_sums, N);
        scan_carry<<<1, 256, 0, stream>>>(blk_sums, B);
        scan_add<<<B, 256, 0, stream>>>(row_ptr, blk_sums, row_fill, N, E);
        scatter_kernel<<<(E + 255) / 256, 256, 0, stream>>>(
            esrc, edst, evalv, row_fill, csr_sv, E);
    }
    if (use_mfma) {
        int total = L * D * D;
        wt_convert<<<(total + 255) / 256, 256, 0, stream>>>(
            Wsum, Wprod, WTsum, WTprod, total);
    }

    const float* ego     = emb;
    const float* spmm_in = emb;
    for (int l = 0; l < L; ++l) {
        if (use_csr) {
            spmm_csr<<<(N + 7) / 8, 256, 0, stream>>>(
                spmm_in, row_ptr, csr_sv, side, N);
        } else {
            hipMemsetAsync(side, 0, ND * sizeof(float), stream);
            long long total  = (long long)E * 32;
            long long blocks = (total + 255) / 256;
            spmm_atomic<<<(int)blocks, 256, 0, stream>>>(spmm_in, esrc, edst, evalv,
                                                         side, total);
        }

        float* norm_out = out + (size_t)(l + 1) * ND;
        float* ego_out  = (l + 1 < L) ? ego_buf : nullptr;
        if (use_mfma) {
            fused_layer_mfma<<<(N + MROWS - 1) / MROWS, 256, 0, stream>>>(
                ego, side,
                WTsum + (size_t)l * D * D, bsum + (size_t)l * D,
                WTprod + (size_t)l * D * D, bprod + (size_t)l * D,
                ego_out, norm_out, N);
        } else {
            fused_layer_f32<<<(N + ROWS - 1) / ROWS, 256, 0, stream>>>(
                ego, side,
                Wsum + (size_t)l * D * D, bsum + (size_t)l * D,
                Wprod + (size_t)l * D * D, bprod + (size_t)l * D,
                ego_out, norm_out, N);
        }

        ego     = ego_buf;
        spmm_in = norm_out;
    }
}

// Round 2
// 722.390 us; speedup vs baseline: 1.0750x; 1.0750x over previous
//
#include <hip/hip_runtime.h>

#define D_DIM 128
#define ROWS 32        // fp32 fallback tile
#define MROWS 64       // mfma kernel rows per block
#define ZPAD 136       // bf16 elems per LDS row: 272 B = 16B-aligned, low bank conflict

typedef __bf16 bf16x8 __attribute__((ext_vector_type(8)));
typedef __bf16 bf16x4 __attribute__((ext_vector_type(4)));
typedef float  f32x4  __attribute__((ext_vector_type(4)));

// ---------------------------------------------------------------------------
// Fallback SpMM (atomic): side[dst] += val * x[src]
// ---------------------------------------------------------------------------
__global__ __launch_bounds__(256) void spmm_atomic(
    const float* __restrict__ x, const int* __restrict__ src,
    const int* __restrict__ dst, const float* __restrict__ val,
    float* __restrict__ side, long long total)
{
    long long i = (long long)blockIdx.x * blockDim.x + threadIdx.x;
    if (i >= total) return;
    int e = (int)(i >> 5);
    int q = (int)(i & 31);
    int s = src[e];
    int d = dst[e];
    float v = val[e];
    const float4 xv = *reinterpret_cast<const float4*>(x + (long long)s * D_DIM + q * 4);
    float* o = side + (long long)d * D_DIM + q * 4;
    unsafeAtomicAdd(o + 0, v * xv.x);
    unsafeAtomicAdd(o + 1, v * xv.y);
    unsafeAtomicAdd(o + 2, v * xv.z);
    unsafeAtomicAdd(o + 3, v * xv.w);
}

// ---------------------------------------------------------------------------
// CSR build: histogram -> exclusive scan -> scatter
// ---------------------------------------------------------------------------
__global__ __launch_bounds__(256) void hist_kernel(
    const int* __restrict__ dst, int* __restrict__ cnt, int E)
{
    int i = blockIdx.x * 256 + threadIdx.x;
    if (i < E) atomicAdd(&cnt[dst[i]], 1);
}

__global__ __launch_bounds__(256) void scan_blocks(
    const int* __restrict__ cnt, int* __restrict__ row_ptr,
    int* __restrict__ blk_sums, int N)
{
    __shared__ int sh[256];
    int i = blockIdx.x * 256 + threadIdx.x;
    int v = (i < N) ? cnt[i] : 0;
    sh[threadIdx.x] = v;
    __syncthreads();
#pragma unroll
    for (int off = 1; off < 256; off <<= 1) {
        int t = (threadIdx.x >= off) ? sh[threadIdx.x - off] : 0;
        __syncthreads();
        sh[threadIdx.x] += t;
        __syncthreads();
    }
    if (i < N) row_ptr[i] = sh[threadIdx.x] - v;
    if (threadIdx.x == 255) blk_sums[blockIdx.x] = sh[255];
}

__global__ __launch_bounds__(256) void scan_carry(int* __restrict__ blk, int B)
{
    __shared__ int sh[256];
    __shared__ int carry;
    if (threadIdx.x == 0) carry = 0;
    __syncthreads();
    for (int base = 0; base < B; base += 256) {
        int i = base + threadIdx.x;
        int v = (i < B) ? blk[i] : 0;
        sh[threadIdx.x] = v;
        __syncthreads();
#pragma unroll
        for (int off = 1; off < 256; off <<= 1) {
            int t = (threadIdx.x >= off) ? sh[threadIdx.x - off] : 0;
            __syncthreads();
            sh[threadIdx.x] += t;
            __syncthreads();
        }
        int excl = sh[threadIdx.x] - v + carry;
        if (i < B) blk[i] = excl;
        __syncthreads();
        if (threadIdx.x == 255) carry = carry + sh[255];
        __syncthreads();
    }
}

__global__ __launch_bounds__(256) void scan_add(
    int* __restrict__ row_ptr, const int* __restrict__ blk_sums,
    int* __restrict__ row_fill, int N, int E)
{
    int i = blockIdx.x * 256 + threadIdx.x;
    if (i < N) {
        int v = row_ptr[i] + blk_sums[i >> 8];
        row_ptr[i]  = v;
        row_fill[i] = v;
    }
    if (i == 0) row_ptr[N] = E;
}

// Interleaved (src, val-as-int) pairs: one 8B random store per edge, and one
// 8B load per edge in the SpMM.
__global__ __launch_bounds__(256) void scatter_kernel(
    const int* __restrict__ src, const int* __restrict__ dst,
    const float* __restrict__ val, int* __restrict__ row_fill,
    int2* __restrict__ csr_sv, int E)
{
    int e = blockIdx.x * 256 + threadIdx.x;
    if (e >= E) return;
    int d = dst[e];
    int pos = atomicAdd(&row_fill[d], 1);
    csr_sv[pos] = make_int2(src[e], __float_as_int(val[e]));
}

// ---------------------------------------------------------------------------
// W^T bf16 precompute: WT[l][n][k] = bf16(W[l][k][n]), both matrices.
// ---------------------------------------------------------------------------
__global__ __launch_bounds__(256) void wt_convert(
    const float* __restrict__ Wsum, const float* __restrict__ Wprod,
    __bf16* __restrict__ WTsum, __bf16* __restrict__ WTprod, int total)
{
    int i = blockIdx.x * 256 + threadIdx.x;
    if (i >= total) return;
    int l  = i >> 14;
    int nk = i & 16383;
    int n  = nk >> 7;
    int k  = nk & 127;
    int widx = (l << 14) + (k << 7) + n;
    WTsum[i]  = (__bf16)Wsum[widx];
    WTprod[i] = (__bf16)Wprod[widx];
}

// ---------------------------------------------------------------------------
// emb prep: out[0] = emb (fp32)  AND  xbf = bf16(emb), one read of emb.
// ---------------------------------------------------------------------------
__global__ __launch_bounds__(256) void emb_prep(
    const float* __restrict__ emb, float* __restrict__ out0,
    __bf16* __restrict__ xbf, long long n4)
{
    long long i = (long long)blockIdx.x * 256 + threadIdx.x;
    if (i >= n4) return;
    float4 v = reinterpret_cast<const float4*>(emb)[i];
    reinterpret_cast<float4*>(out0)[i] = v;
    bf16x4 b;
    b[0] = (__bf16)v.x; b[1] = (__bf16)v.y;
    b[2] = (__bf16)v.z; b[3] = (__bf16)v.w;
    reinterpret_cast<bf16x4*>(xbf)[i] = b;
}

// ---------------------------------------------------------------------------
// CSR SpMM, bf16 gather payload: one 32-lane group per dst row; 8-deep MLP.
// Gather bytes halved vs fp32 (256B/edge): the dominant byte stream.
// fp32 accumulate -> side stays fp32.
// ---------------------------------------------------------------------------
__global__ __launch_bounds__(256) void spmm_csr_bf16(
    const __bf16* __restrict__ x, const int* __restrict__ row_ptr,
    const int2* __restrict__ csr_sv, float* __restrict__ side, int N)
{
    int row  = blockIdx.x * 8 + (threadIdx.x >> 5);
    int lane = threadIdx.x & 31;
    if (row >= N) return;
    int start = row_ptr[row];
    int end   = row_ptr[row + 1];
    const __bf16* xl = x + lane * 4;
    float4 acc = make_float4(0.f, 0.f, 0.f, 0.f);
    int j = start;
    for (; j + 8 <= end; j += 8) {
        int2 sv0 = csr_sv[j + 0], sv1 = csr_sv[j + 1];
        int2 sv2 = csr_sv[j + 2], sv3 = csr_sv[j + 3];
        int2 sv4 = csr_sv[j + 4], sv5 = csr_sv[j + 5];
        int2 sv6 = csr_sv[j + 6], sv7 = csr_sv[j + 7];
        bf16x4 b0 = *reinterpret_cast<const bf16x4*>(xl + (long long)sv0.x * D_DIM);
        bf16x4 b1 = *reinterpret_cast<const bf16x4*>(xl + (long long)sv1.x * D_DIM);
        bf16x4 b2 = *reinterpret_cast<const bf16x4*>(xl + (long long)sv2.x * D_DIM);
        bf16x4 b3 = *reinterpret_cast<const bf16x4*>(xl + (long long)sv3.x * D_DIM);
        bf16x4 b4 = *reinterpret_cast<const bf16x4*>(xl + (long long)sv4.x * D_DIM);
        bf16x4 b5 = *reinterpret_cast<const bf16x4*>(xl + (long long)sv5.x * D_DIM);
        bf16x4 b6 = *reinterpret_cast<const bf16x4*>(xl + (long long)sv6.x * D_DIM);
        bf16x4 b7 = *reinterpret_cast<const bf16x4*>(xl + (long long)sv7.x * D_DIM);
        float v0 = __int_as_float(sv0.y), v1 = __int_as_float(sv1.y);
        float v2 = __int_as_float(sv2.y), v3 = __int_as_float(sv3.y);
        float v4 = __int_as_float(sv4.y), v5 = __int_as_float(sv5.y);
        float v6 = __int_as_float(sv6.y), v7 = __int_as_float(sv7.y);
        acc.x += v0 * (float)b0[0] + v1 * (float)b1[0] + v2 * (float)b2[0] + v3 * (float)b3[0];
        acc.y += v0 * (float)b0[1] + v1 * (float)b1[1] + v2 * (float)b2[1] + v3 * (float)b3[1];
        acc.z += v0 * (float)b0[2] + v1 * (float)b1[2] + v2 * (float)b2[2] + v3 * (float)b3[2];
        acc.w += v0 * (float)b0[3] + v1 * (float)b1[3] + v2 * (float)b2[3] + v3 * (float)b3[3];
        acc.x += v4 * (float)b4[0] + v5 * (float)b5[0] + v6 * (float)b6[0] + v7 * (float)b7[0];
        acc.y += v4 * (float)b4[1] + v5 * (float)b5[1] + v6 * (float)b6[1] + v7 * (float)b7[1];
        acc.z += v4 * (float)b4[2] + v5 * (float)b5[2] + v6 * (float)b6[2] + v7 * (float)b7[2];
        acc.w += v4 * (float)b4[3] + v5 * (float)b5[3] + v6 * (float)b6[3] + v7 * (float)b7[3];
    }
    for (; j + 4 <= end; j += 4) {
        int2 sv0 = csr_sv[j + 0], sv1 = csr_sv[j + 1];
        int2 sv2 = csr_sv[j + 2], sv3 = csr_sv[j + 3];
        bf16x4 b0 = *reinterpret_cast<const bf16x4*>(xl + (long long)sv0.x * D_DIM);
        bf16x4 b1 = *reinterpret_cast<const bf16x4*>(xl + (long long)sv1.x * D_DIM);
        bf16x4 b2 = *reinterpret_cast<const bf16x4*>(xl + (long long)sv2.x * D_DIM);
        bf16x4 b3 = *reinterpret_cast<const bf16x4*>(xl + (long long)sv3.x * D_DIM);
        float v0 = __int_as_float(sv0.y), v1 = __int_as_float(sv1.y);
        float v2 = __int_as_float(sv2.y), v3 = __int_as_float(sv3.y);
        acc.x += v0 * (float)b0[0] + v1 * (float)b1[0] + v2 * (float)b2[0] + v3 * (float)b3[0];
        acc.y += v0 * (float)b0[1] + v1 * (float)b1[1] + v2 * (float)b2[1] + v3 * (float)b3[1];
        acc.z += v0 * (float)b0[2] + v1 * (float)b1[2] + v2 * (float)b2[2] + v3 * (float)b3[2];
        acc.w += v0 * (float)b0[3] + v1 * (float)b1[3] + v2 * (float)b2[3] + v3 * (float)b3[3];
    }
    for (; j < end; ++j) {
        int2 sv = csr_sv[j];
        float v = __int_as_float(sv.y);
        bf16x4 b = *reinterpret_cast<const bf16x4*>(xl + (long long)sv.x * D_DIM);
        acc.x += v * (float)b[0];
        acc.y += v * (float)b[1];
        acc.z += v * (float)b[2];
        acc.w += v * (float)b[3];
    }
    *reinterpret_cast<float4*>(side + (long long)row * D_DIM + lane * 4) = acc;
}

// fp32 fallback CSR SpMM (used when mfma/bf16 workspace unavailable)
__global__ __launch_bounds__(256) void spmm_csr_f32(
    const float* __restrict__ x, const int* __restrict__ row_ptr,
    const int2* __restrict__ csr_sv, float* __restrict__ side, int N)
{
    int row  = blockIdx.x * 8 + (threadIdx.x >> 5);
    int lane = threadIdx.x & 31;
    if (row >= N) return;
    int start = row_ptr[row];
    int end   = row_ptr[row + 1];
    const float* xl = x + lane * 4;
    float4 acc = make_float4(0.f, 0.f, 0.f, 0.f);
    int j = start;
    for (; j + 4 <= end; j += 4) {
        int2 sv0 = csr_sv[j + 0], sv1 = csr_sv[j + 1];
        int2 sv2 = csr_sv[j + 2], sv3 = csr_sv[j + 3];
        const float4 x0 = *reinterpret_cast<const float4*>(xl + (long long)sv0.x * D_DIM);
        const float4 x1 = *reinterpret_cast<const float4*>(xl + (long long)sv1.x * D_DIM);
        const float4 x2 = *reinterpret_cast<const float4*>(xl + (long long)sv2.x * D_DIM);
        const float4 x3 = *reinterpret_cast<const float4*>(xl + (long long)sv3.x * D_DIM);
        float v0 = __int_as_float(sv0.y), v1 = __int_as_float(sv1.y);
        float v2 = __int_as_float(sv2.y), v3 = __int_as_float(sv3.y);
        acc.x += v0 * x0.x + v1 * x1.x + v2 * x2.x + v3 * x3.x;
        acc.y += v0 * x0.y + v1 * x1.y + v2 * x2.y + v3 * x3.y;
        acc.z += v0 * x0.z + v1 * x1.z + v2 * x2.z + v3 * x3.z;
        acc.w += v0 * x0.w + v1 * x1.w + v2 * x2.w + v3 * x3.w;
    }
    for (; j < end; ++j) {
        int2 sv = csr_sv[j];
        float v = __int_as_float(sv.y);
        const float4 xv = *reinterpret_cast<const float4*>(xl + (long long)sv.x * D_DIM);
        acc.x += v * xv.x;
        acc.y += v * xv.y;
        acc.z += v * xv.z;
        acc.w += v * xv.w;
    }
    *reinterpret_cast<float4*>(side + (long long)row * D_DIM + lane * 4) = acc;
}

// ---------------------------------------------------------------------------
// MFMA fused BiAggregator layer.
//   Block: 256 thr = 4 waves; 64 rows x 128 cols. Wave w: rows w*16..w*16+15.
//   z=ego+side, m=ego*side staged as bf16 in LDS (full K=128, one barrier).
//   B-frags read from pre-transposed bf16 WT (global, L2-resident).
//   mfma_f32_16x16x32_bf16: A[m=lane&15][k=quad*8+j]; D: col=lane&15,
//   row=quad*4+reg (m89/m120-verified layouts).
//   nbf_out (optional): bf16 copy of normalized output = next layer's SpMM in.
// ---------------------------------------------------------------------------
__global__ __launch_bounds__(256) void fused_layer_mfma(
    const float* __restrict__ ego, const float* __restrict__ side,
    const __bf16* __restrict__ WTsum, const float* __restrict__ bsum,
    const __bf16* __restrict__ WTprod, const float* __restrict__ bprod,
    float* __restrict__ ego_out,   // may be nullptr (last layer)
    float* __restrict__ norm_out,
    __bf16* __restrict__ nbf_out,  // may be nullptr (last layer)
    int N)
{
    __shared__ __bf16 zt[MROWS][ZPAD];
    __shared__ __bf16 mt[MROWS][ZPAD];

    const int tid  = threadIdx.x;
    const int row0 = blockIdx.x * MROWS;

    // ---- stage z, m as bf16 (each thread 8 float4-pairs) ----
    for (int idx = tid; idx < MROWS * 32; idx += 256) {
        int r = idx >> 5, q = idx & 31;
        int row = row0 + r;
        float4 e4 = make_float4(0.f, 0.f, 0.f, 0.f);
        float4 s4 = make_float4(0.f, 0.f, 0.f, 0.f);
        if (row < N) {
            e4 = *reinterpret_cast<const float4*>(ego  + (long long)row * D_DIM + q * 4);
            s4 = *reinterpret_cast<const float4*>(side + (long long)row * D_DIM + q * 4);
        }
        bf16x4 z4, m4;
        z4[0] = (__bf16)(e4.x + s4.x); z4[1] = (__bf16)(e4.y + s4.y);
        z4[2] = (__bf16)(e4.z + s4.z); z4[3] = (__bf16)(e4.w + s4.w);
        m4[0] = (__bf16)(e4.x * s4.x); m4[1] = (__bf16)(e4.y * s4.y);
        m4[2] = (__bf16)(e4.z * s4.z); m4[3] = (__bf16)(e4.w * s4.w);
        *reinterpret_cast<bf16x4*>(&zt[r][q * 4]) = z4;
        *reinterpret_cast<bf16x4*>(&mt[r][q * 4]) = m4;
    }
    __syncthreads();

    const int wave = tid >> 6;
    const int lane = tid & 63;
    const int ln   = lane & 15;        // n within tile / m within A
    const int quad = lane >> 4;        // k-block selector (A/B), row-block (C)
    const int mloc = wave * 16;        // this wave's row base within block

    f32x4 acc_s[8], acc_p[8];
#pragma unroll
    for (int nt = 0; nt < 8; ++nt) {
        acc_s[nt] = (f32x4){0.f, 0.f, 0.f, 0.f};
        acc_p[nt] = (f32x4){0.f, 0.f, 0.f, 0.f};
    }

#pragma unroll
    for (int ks = 0; ks < 4; ++ks) {
        const int k0 = ks * 32 + quad * 8;
        bf16x8 az = *reinterpret_cast<const bf16x8*>(&zt[mloc + ln][k0]);
        bf16x8 am = *reinterpret_cast<const bf16x8*>(&mt[mloc + ln][k0]);
#pragma unroll
        for (int nt = 0; nt < 8; ++nt) {
            const long long wofs = (long long)(nt * 16 + ln) * D_DIM + k0;
            bf16x8 bs = *reinterpret_cast<const bf16x8*>(WTsum  + wofs);
            bf16x8 bp = *reinterpret_cast<const bf16x8*>(WTprod + wofs);
            acc_s[nt] = __builtin_amdgcn_mfma_f32_16x16x32_bf16(az, bs, acc_s[nt], 0, 0, 0);
            acc_p[nt] = __builtin_amdgcn_mfma_f32_16x16x32_bf16(am, bp, acc_p[nt], 0, 0, 0);
        }
    }

    // ---- epilogue: bias + lrelu + add, row L2-norm, stores ----
    float bsv[8], bpv[8];
#pragma unroll
    for (int nt = 0; nt < 8; ++nt) {
        bsv[nt] = bsum[nt * 16 + ln];
        bpv[nt] = bprod[nt * 16 + ln];
    }
    float part[4] = {0.f, 0.f, 0.f, 0.f};
#pragma unroll
    for (int nt = 0; nt < 8; ++nt) {
#pragma unroll
        for (int r = 0; r < 4; ++r) {
            float sv = acc_s[nt][r] + bsv[nt];
            sv = sv > 0.f ? sv : 0.01f * sv;
            float pv = acc_p[nt][r] + bpv[nt];
            pv = pv > 0.f ? pv : 0.01f * pv;
            float e = sv + pv;
            acc_s[nt][r] = e;           // reuse as e-store
            part[r] += e * e;
        }
    }
#pragma unroll
    for (int off = 1; off < 16; off <<= 1) {
#pragma unroll
        for (int r = 0; r < 4; ++r)
            part[r] += __shfl_xor(part[r], off, 16);
    }
#pragma unroll
    for (int r = 0; r < 4; ++r) {
        int row = row0 + mloc + quad * 4 + r;
        if (row >= N) continue;
        float inv = 1.0f / fmaxf(sqrtf(part[r]), 1e-12f);
        long long base = (long long)row * D_DIM + ln;
#pragma unroll
        for (int nt = 0; nt < 8; ++nt)
            norm_out[base + nt * 16] = acc_s[nt][r] * inv;
        if (nbf_out) {
#pragma unroll
            for (int nt = 0; nt < 8; ++nt)
                nbf_out[base + nt * 16] = (__bf16)(acc_s[nt][r] * inv);
        }
        if (ego_out) {
#pragma unroll
            for (int nt = 0; nt < 8; ++nt)
                ego_out[base + nt * 16] = acc_s[nt][r];
        }
    }
}

// ---------------------------------------------------------------------------
// fp32 fallback fused layer (R1 version)
// ---------------------------------------------------------------------------
__global__ __launch_bounds__(256) void fused_layer_f32(
    const float* __restrict__ ego, const float* __restrict__ side,
    const float* __restrict__ Wsum, const float* __restrict__ bsum,
    const float* __restrict__ Wprod, const float* __restrict__ bprod,
    float* __restrict__ ego_out, float* __restrict__ norm_out, int N)
{
    __shared__ float zt[ROWS][D_DIM];
    __shared__ float mt[ROWS][D_DIM];
    __shared__ float wsh[32][D_DIM];
    __shared__ float wph[32][D_DIM];

    const int tid  = threadIdx.x;
    const int row0 = blockIdx.x * ROWS;
    const int cg   = tid & 31;
    const int rg   = tid >> 5;

    for (int idx = tid; idx < ROWS * 32; idx += 256) {
        int r = idx >> 5, q = idx & 31;
        int row = row0 + r;
        float4 e4 = make_float4(0.f, 0.f, 0.f, 0.f);
        float4 s4 = make_float4(0.f, 0.f, 0.f, 0.f);
        if (row < N) {
            e4 = *reinterpret_cast<const float4*>(ego  + (long long)row * D_DIM + q * 4);
            s4 = *reinterpret_cast<const float4*>(side + (long long)row * D_DIM + q * 4);
        }
        float4 z4 = make_float4(e4.x + s4.x, e4.y + s4.y, e4.z + s4.z, e4.w + s4.w);
        float4 m4 = make_float4(e4.x * s4.x, e4.y * s4.y, e4.z * s4.z, e4.w * s4.w);
        *reinterpret_cast<float4*>(&zt[r][q * 4]) = z4;
        *reinterpret_cast<float4*>(&mt[r][q * 4]) = m4;
    }

    float acc_s[4][4], acc_p[4][4];
#pragma unroll
    for (int a = 0; a < 4; ++a)
#pragma unroll
        for (int b = 0; b < 4; ++b) { acc_s[a][b] = 0.f; acc_p[a][b] = 0.f; }

    for (int kc = 0; kc < D_DIM; kc += 32) {
        __syncthreads();
        for (int idx = tid; idx < 32 * 32; idx += 256) {
            int kk = idx >> 5, q = idx & 31;
            *reinterpret_cast<float4*>(&wsh[kk][q * 4]) =
                *reinterpret_cast<const float4*>(Wsum + (long long)(kc + kk) * D_DIM + q * 4);
            *reinterpret_cast<float4*>(&wph[kk][q * 4]) =
                *reinterpret_cast<const float4*>(Wprod + (long long)(kc + kk) * D_DIM + q * 4);
        }
        __syncthreads();
#pragma unroll 8
        for (int kk = 0; kk < 32; ++kk) {
            float4 w_s = *reinterpret_cast<const float4*>(&wsh[kk][cg * 4]);
            float4 w_p = *reinterpret_cast<const float4*>(&wph[kk][cg * 4]);
#pragma unroll
            for (int rr = 0; rr < 4; ++rr) {
                float z = zt[rg * 4 + rr][kc + kk];
                float m = mt[rg * 4 + rr][kc + kk];
                acc_s[rr][0] += z * w_s.x; acc_s[rr][1] += z * w_s.y;
                acc_s[rr][2] += z * w_s.z; acc_s[rr][3] += z * w_s.w;
                acc_p[rr][0] += m * w_p.x; acc_p[rr][1] += m * w_p.y;
                acc_p[rr][2] += m * w_p.z; acc_p[rr][3] += m * w_p.w;
            }
        }
    }

    const float4 bs = *reinterpret_cast<const float4*>(bsum  + cg * 4);
    const float4 bp = *reinterpret_cast<const float4*>(bprod + cg * 4);
    float ev[4][4];
    float part[4];
#pragma unroll
    for (int rr = 0; rr < 4; ++rr) {
        float bsv[4] = {bs.x, bs.y, bs.z, bs.w};
        float bpv[4] = {bp.x, bp.y, bp.z, bp.w};
        float acc = 0.f;
#pragma unroll
        for (int cc = 0; cc < 4; ++cc) {
            float sv = acc_s[rr][cc] + bsv[cc];
            sv = sv > 0.f ? sv : 0.01f * sv;
            float pv = acc_p[rr][cc] + bpv[cc];
            pv = pv > 0.f ? pv : 0.01f * pv;
            float e = sv + pv;
            ev[rr][cc] = e;
            acc += e * e;
        }
        part[rr] = acc;
    }
#pragma unroll
    for (int off = 1; off < 32; off <<= 1) {
#pragma unroll
        for (int rr = 0; rr < 4; ++rr)
            part[rr] += __shfl_xor(part[rr], off, 32);
    }
#pragma unroll
    for (int rr = 0; rr < 4; ++rr) {
        int row = row0 + rg * 4 + rr;
        if (row >= N) continue;
        float inv = 1.0f / fmaxf(sqrtf(part[rr]), 1e-12f);
        float4 o  = make_float4(ev[rr][0] * inv, ev[rr][1] * inv,
                                ev[rr][2] * inv, ev[rr][3] * inv);
        *reinterpret_cast<float4*>(norm_out + (long long)row * D_DIM + cg * 4) = o;
        if (ego_out) {
            float4 g = make_float4(ev[rr][0], ev[rr][1], ev[rr][2], ev[rr][3]);
            *reinterpret_cast<float4*>(ego_out + (long long)row * D_DIM + cg * 4) = g;
        }
    }
}

// ---------------------------------------------------------------------------
extern "C" void kernel_launch(void* const* d_in, const int* in_sizes, int n_in,
                              void* d_out, int out_size, void* d_ws, size_t ws_size,
                              hipStream_t stream)
{
    const float* emb   = (const float*)d_in[0];
    const int*   esrc  = (const int*)  d_in[1];
    const int*   edst  = (const int*)  d_in[2];
    const float* evalv = (const float*)d_in[3];
    const float* Wsum  = (const float*)d_in[4];
    const float* bsum  = (const float*)d_in[5];
    const float* Wprod = (const float*)d_in[6];
    const float* bprod = (const float*)d_in[7];
    float* out = (float*)d_out;

    const int D = 128;
    const int N = in_sizes[0] / D;
    const int E = in_sizes[1];
    const int L = in_sizes[5] / D;
    const size_t ND = (size_t)N * D;
    const int B = (N + 255) / 256;

    // workspace layout
    char* ws = (char*)d_ws;
    float* side    = (float*)ws;                 ws += ND * sizeof(float);
    float* ego_buf = (float*)ws;                 ws += ND * sizeof(float);
    int*   row_ptr  = (int*)ws;                  ws += (size_t)(N + 1) * sizeof(int);
    int*   row_fill = (int*)ws;                  ws += (size_t)N * sizeof(int);
    int*   blk_sums = (int*)ws;                  ws += (size_t)B * sizeof(int);
    ws = (char*)(((uintptr_t)ws + 15) & ~(uintptr_t)15);   // align for int2/vec
    int2*  csr_sv   = (int2*)ws;                 ws += (size_t)E * sizeof(int2);
    size_t csr_bytes = (size_t)(ws - (char*)d_ws);
    __bf16* WTsum  = (__bf16*)ws;                ws += (size_t)L * D * D * sizeof(__bf16);
    __bf16* WTprod = (__bf16*)ws;                ws += (size_t)L * D * D * sizeof(__bf16);
    __bf16* xbf    = (__bf16*)ws;                ws += ND * sizeof(__bf16);
    size_t mfma_bytes = (size_t)(ws - (char*)d_ws);

    const bool use_csr  = (ws_size >= csr_bytes);
    const bool use_mfma = (ws_size >= mfma_bytes);

    // out[0] = embeddings (+ bf16 copy for SpMM when mfma path active)
    if (use_mfma) {
        long long n4 = (long long)(ND / 4);
        emb_prep<<<(int)((n4 + 255) / 256), 256, 0, stream>>>(emb, out, xbf, n4);
        int total = L * D * D;
        wt_convert<<<(total + 255) / 256, 256, 0, stream>>>(
            Wsum, Wprod, WTsum, WTprod, total);
    } else {
        hipMemcpyAsync(out, emb, ND * sizeof(float), hipMemcpyDeviceToDevice, stream);
    }

    if (use_csr) {
        hipMemsetAsync(row_fill, 0, (size_t)N * sizeof(int), stream);
        hist_kernel<<<(E + 255) / 256, 256, 0, stream>>>(edst, row_fill, E);
        scan_blocks<<<B, 256, 0, stream>>>(row_fill, row_ptr, blk_sums, N);
        scan_carry<<<1, 256, 0, stream>>>(blk_sums, B);
        scan_add<<<B, 256, 0, stream>>>(row_ptr, blk_sums, row_fill, N, E);
        scatter_kernel<<<(E + 255) / 256, 256, 0, stream>>>(
            esrc, edst, evalv, row_fill, csr_sv, E);
    }

    const float* ego     = emb;
    const float* spmm_in = emb;   // fp32 spmm input (fallback paths)
    for (int l = 0; l < L; ++l) {
        if (use_csr) {
            if (use_mfma) {
                spmm_csr_bf16<<<(N + 7) / 8, 256, 0, stream>>>(
                    xbf, row_ptr, csr_sv, side, N);
            } else {
                spmm_csr_f32<<<(N + 7) / 8, 256, 0, stream>>>(
                    spmm_in, row_ptr, csr_sv, side, N);
            }
        } else {
            hipMemsetAsync(side, 0, ND * sizeof(float), stream);
            long long total  = (long long)E * 32;
            long long blocks = (total + 255) / 256;
            spmm_atomic<<<(int)blocks, 256, 0, stream>>>(spmm_in, esrc, edst, evalv,
                                                         side, total);
        }

        float* norm_out = out + (size_t)(l + 1) * ND;
        float* ego_out  = (l + 1 < L) ? ego_buf : nullptr;
        if (use_mfma) {
            __bf16* nbf = (l + 1 < L) ? xbf : nullptr;  // next layer's SpMM input
            fused_layer_mfma<<<(N + MROWS - 1) / MROWS, 256, 0, stream>>>(
                ego, side,
                WTsum + (size_t)l * D * D, bsum + (size_t)l * D,
                WTprod + (size_t)l * D * D, bprod + (size_t)l * D,
                ego_out, norm_out, nbf, N);
        } else {
            fused_layer_f32<<<(N + ROWS - 1) / ROWS, 256, 0, stream>>>(
                ego, side,
                Wsum + (size_t)l * D * D, bsum + (size_t)l * D,
                Wprod + (size_t)l * D * D, bprod + (size_t)l * D,
                ego_out, norm_out, N);
        }

        ego     = ego_buf;
        spmm_in = norm_out;
    }
}

// Round 3
// 625.100 us; speedup vs baseline: 1.2423x; 1.1556x over previous
//
#include <hip/hip_runtime.h>

#define D_DIM 128
#define ROWS 32        // fp32 fallback tile
#define MROWS 64       // mfma kernel rows per block
#define ZPAD 136       // bf16 elems per LDS row: 272 B = 16B-aligned, low bank conflict

#define BSH 7                    // rows per bucket = 128
#define BROWS (1 << BSH)
#define NB_MAX 2048              // bucket-path guard: NB <= 2048
#define CHUNK 4096               // edges per block in bucket count/scatter

typedef __bf16 bf16x8 __attribute__((ext_vector_type(8)));
typedef __bf16 bf16x4 __attribute__((ext_vector_type(4)));
typedef float  f32x4  __attribute__((ext_vector_type(4)));

// ---------------------------------------------------------------------------
// Fallback SpMM (atomic): side[dst] += val * x[src]
// ---------------------------------------------------------------------------
__global__ __launch_bounds__(256) void spmm_atomic(
    const float* __restrict__ x, const int* __restrict__ src,
    const int* __restrict__ dst, const float* __restrict__ val,
    float* __restrict__ side, long long total)
{
    long long i = (long long)blockIdx.x * blockDim.x + threadIdx.x;
    if (i >= total) return;
    int e = (int)(i >> 5);
    int q = (int)(i & 31);
    int s = src[e];
    int d = dst[e];
    float v = val[e];
    const float4 xv = *reinterpret_cast<const float4*>(x + (long long)s * D_DIM + q * 4);
    float* o = side + (long long)d * D_DIM + q * 4;
    unsafeAtomicAdd(o + 0, v * xv.x);
    unsafeAtomicAdd(o + 1, v * xv.y);
    unsafeAtomicAdd(o + 2, v * xv.z);
    unsafeAtomicAdd(o + 3, v * xv.w);
}

// ---------------------------------------------------------------------------
// OLD CSR build (fallback): histogram -> exclusive scan -> scatter
// ---------------------------------------------------------------------------
__global__ __launch_bounds__(256) void hist_kernel(
    const int* __restrict__ dst, int* __restrict__ cnt, int E)
{
    int i = blockIdx.x * 256 + threadIdx.x;
    if (i < E) atomicAdd(&cnt[dst[i]], 1);
}

__global__ __launch_bounds__(256) void scan_blocks(
    const int* __restrict__ cnt, int* __restrict__ row_ptr,
    int* __restrict__ blk_sums, int N)
{
    __shared__ int sh[256];
    int i = blockIdx.x * 256 + threadIdx.x;
    int v = (i < N) ? cnt[i] : 0;
    sh[threadIdx.x] = v;
    __syncthreads();
#pragma unroll
    for (int off = 1; off < 256; off <<= 1) {
        int t = (threadIdx.x >= off) ? sh[threadIdx.x - off] : 0;
        __syncthreads();
        sh[threadIdx.x] += t;
        __syncthreads();
    }
    if (i < N) row_ptr[i] = sh[threadIdx.x] - v;
    if (threadIdx.x == 255) blk_sums[blockIdx.x] = sh[255];
}

__global__ __launch_bounds__(256) void scan_carry(int* __restrict__ blk, int B)
{
    __shared__ int sh[256];
    __shared__ int carry;
    if (threadIdx.x == 0) carry = 0;
    __syncthreads();
    for (int base = 0; base < B; base += 256) {
        int i = base + threadIdx.x;
        int v = (i < B) ? blk[i] : 0;
        sh[threadIdx.x] = v;
        __syncthreads();
#pragma unroll
        for (int off = 1; off < 256; off <<= 1) {
            int t = (threadIdx.x >= off) ? sh[threadIdx.x - off] : 0;
            __syncthreads();
            sh[threadIdx.x] += t;
            __syncthreads();
        }
        int excl = sh[threadIdx.x] - v + carry;
        if (i < B) blk[i] = excl;
        __syncthreads();
        if (threadIdx.x == 255) carry = carry + sh[255];
        __syncthreads();
    }
}

__global__ __launch_bounds__(256) void scan_add(
    int* __restrict__ row_ptr, const int* __restrict__ blk_sums,
    int* __restrict__ row_fill, int N, int E)
{
    int i = blockIdx.x * 256 + threadIdx.x;
    if (i < N) {
        int v = row_ptr[i] + blk_sums[i >> 8];
        row_ptr[i]  = v;
        row_fill[i] = v;
    }
    if (i == 0) row_ptr[N] = E;
}

__global__ __launch_bounds__(256) void scatter_kernel(
    const int* __restrict__ src, const int* __restrict__ dst,
    const float* __restrict__ val, int* __restrict__ row_fill,
    int2* __restrict__ csr_sv, int E)
{
    int e = blockIdx.x * 256 + threadIdx.x;
    if (e >= E) return;
    int d = dst[e];
    int pos = atomicAdd(&row_fill[d], 1);
    csr_sv[pos] = make_int2(src[e], __float_as_int(val[e]));
}

// ---------------------------------------------------------------------------
// NEW bucket-based CSR build: all per-row ranking atomics live in LDS.
//   bucket = dst >> BSH (128 rows/bucket). 4 kernels:
//   1) bucket_count: LDS hist per block -> global adds (no return).
//   2) bucket_scan: exclusive scan of bucket counts (1 block).
//   3) bucket_scatter: per-block LDS counting sort of a CHUNK, one allocation
//      atomic per (block,bucket), coalesced 16B flush into bucket-grouped
//      staging (aliased onto dead `side` buffer).
//   4) bucket_finalize: per bucket: LDS row hist -> scan -> row_ptr; LDS rank
//      -> csr_sv. Stores confined to the bucket's small csr window.
// ---------------------------------------------------------------------------
__global__ __launch_bounds__(256) void bucket_count(
    const int* __restrict__ dst, int* __restrict__ bucket_cnt, int E, int NB)
{
    __shared__ int h[NB_MAX];
    for (int i = threadIdx.x; i < NB; i += 256) h[i] = 0;
    __syncthreads();
    int ebase = blockIdx.x * CHUNK;
    int ecnt  = min(CHUNK, E - ebase);
    for (int i = threadIdx.x; i < ecnt; i += 256)
        atomicAdd(&h[dst[ebase + i] >> BSH], 1);
    __syncthreads();
    for (int i = threadIdx.x; i < NB; i += 256)
        if (h[i]) atomicAdd(&bucket_cnt[i], h[i]);
}

__global__ __launch_bounds__(256) void bucket_scan(
    const int* __restrict__ bucket_cnt, int* __restrict__ bucket_ptr,
    int* __restrict__ bucket_fill, int NB, int E)
{
    __shared__ int sh[256];
    __shared__ int carry;
    if (threadIdx.x == 0) carry = 0;
    __syncthreads();
    for (int base = 0; base < NB; base += 256) {
        int i = base + threadIdx.x;
        int v = (i < NB) ? bucket_cnt[i] : 0;
        sh[threadIdx.x] = v;
        __syncthreads();
#pragma unroll
        for (int off = 1; off < 256; off <<= 1) {
            int t = (threadIdx.x >= off) ? sh[threadIdx.x - off] : 0;
            __syncthreads();
            sh[threadIdx.x] += t;
            __syncthreads();
        }
        if (i < NB) {
            int excl = sh[threadIdx.x] - v + carry;
            bucket_ptr[i]  = excl;
            bucket_fill[i] = excl;
        }
        __syncthreads();
        if (threadIdx.x == 255) carry = carry + sh[255];
        __syncthreads();
    }
    if (threadIdx.x == 0) bucket_ptr[NB] = E;
}

__global__ __launch_bounds__(256) void bucket_scatter(
    const int* __restrict__ src, const int* __restrict__ dst,
    const float* __restrict__ val, int* __restrict__ bucket_fill,
    int* __restrict__ stage,   // int4-strided: [E]{src, val, dst, pad}
    int NB, int E)
{
    __shared__ int hist[NB_MAX];   // counts, then reused as slot cursor
    __shared__ int excl[NB_MAX];
    __shared__ int gbase[NB_MAX];
    __shared__ int psum[256];
    __shared__ int s_src[CHUNK];
    __shared__ int s_val[CHUNK];
    __shared__ int s_dst[CHUNK];

    const int tid   = threadIdx.x;
    const int ebase = blockIdx.x * CHUNK;
    const int ecnt  = min(CHUNK, E - ebase);

    for (int i = tid; i < NB; i += 256) hist[i] = 0;
    __syncthreads();
    // pass 1: histogram by bucket
    for (int i = tid; i < ecnt; i += 256)
        atomicAdd(&hist[dst[ebase + i] >> BSH], 1);
    __syncthreads();
    // exclusive scan of hist[0..NB)
    const int per = (NB + 255) / 256;        // <= 8
    const int t0  = tid * per;
    int tsum = 0;
    for (int k = 0; k < per; ++k) {
        int idx = t0 + k;
        tsum += (idx < NB) ? hist[idx] : 0;
    }
    psum[tid] = tsum;
    __syncthreads();
#pragma unroll
    for (int off = 1; off < 256; off <<= 1) {
        int t = (tid >= off) ? psum[tid - off] : 0;
        __syncthreads();
        psum[tid] += t;
        __syncthreads();
    }
    int run = psum[tid] - tsum;
    for (int k = 0; k < per; ++k) {
        int idx = t0 + k;
        if (idx < NB) { excl[idx] = run; run += hist[idx]; }
    }
    __syncthreads();
    // global allocation (low contention, once per block-bucket)
    for (int i = tid; i < NB; i += 256)
        gbase[i] = hist[i] ? atomicAdd(&bucket_fill[i], hist[i]) : 0;
    __syncthreads();
    // reuse hist as slot cursor = excl
    for (int i = tid; i < NB; i += 256) hist[i] = excl[i];
    __syncthreads();
    // pass 2: re-read edges (L2-hot window), place into bucket-ordered LDS slots
    for (int i = tid; i < ecnt; i += 256) {
        int d = dst[ebase + i];
        int slot = atomicAdd(&hist[d >> BSH], 1);
        s_src[slot] = src[ebase + i];
        s_val[slot] = __float_as_int(val[ebase + i]);
        s_dst[slot] = d;
    }
    __syncthreads();
    // flush: bucket-ordered LDS -> contiguous global runs (coalesced 16B)
    for (int i = tid; i < ecnt; i += 256) {
        int d   = s_dst[i];
        int bkt = d >> BSH;
        int gpos = gbase[bkt] + (i - excl[bkt]);
        *reinterpret_cast<int4*>(stage + 4 * (long long)gpos) =
            make_int4(s_src[i], s_val[i], d, 0);
    }
}

__global__ __launch_bounds__(256) void bucket_finalize(
    const int* __restrict__ stage, const int* __restrict__ bucket_ptr,
    int* __restrict__ row_ptr, int2* __restrict__ csr_sv, int N, int E)
{
    __shared__ int cnt[BROWS];
    __shared__ int rbase[BROWS];

    const int b   = blockIdx.x;
    const int tid = threadIdx.x;
    const int e0  = bucket_ptr[b];
    const int e1  = bucket_ptr[b + 1];
    const int r0  = b << BSH;
    const int nrows = min(BROWS, N - r0);

    if (tid < BROWS) cnt[tid] = 0;
    __syncthreads();
    // pass 1: per-row histogram (LDS atomics)
    for (int i = e0 + tid; i < e1; i += 256)
        atomicAdd(&cnt[stage[4 * (long long)i + 2] & (BROWS - 1)], 1);
    __syncthreads();
    // inclusive scan over BROWS
    if (tid < BROWS) rbase[tid] = cnt[tid];
    __syncthreads();
#pragma unroll
    for (int off = 1; off < BROWS; off <<= 1) {
        int t = 0;
        if (tid < BROWS && tid >= off) t = rbase[tid - off];
        __syncthreads();
        if (tid < BROWS) rbase[tid] += t;
        __syncthreads();
    }
    // exclusive + bucket base; emit row_ptr
    if (tid < BROWS) {
        int excl = e0 + rbase[tid] - cnt[tid];
        rbase[tid] = excl;
        if (tid < nrows) row_ptr[r0 + tid] = excl;
    }
    if (b == 0 && tid == 0) row_ptr[N] = E;
    __syncthreads();
    if (tid < BROWS) cnt[tid] = 0;     // reuse as rank cursor
    __syncthreads();
    // pass 2: rank in LDS, store csr entry (stores confined to bucket window)
    for (int i = e0 + tid; i < e1; i += 256) {
        const int4 t = *reinterpret_cast<const int4*>(stage + 4 * (long long)i);
        int r = t.z & (BROWS - 1);
        int rank = atomicAdd(&cnt[r], 1);
        csr_sv[rbase[r] + rank] = make_int2(t.x, t.y);
    }
}

// ---------------------------------------------------------------------------
// W^T bf16 precompute: WT[l][n][k] = bf16(W[l][k][n]), both matrices.
// ---------------------------------------------------------------------------
__global__ __launch_bounds__(256) void wt_convert(
    const float* __restrict__ Wsum, const float* __restrict__ Wprod,
    __bf16* __restrict__ WTsum, __bf16* __restrict__ WTprod, int total)
{
    int i = blockIdx.x * 256 + threadIdx.x;
    if (i >= total) return;
    int l  = i >> 14;
    int nk = i & 16383;
    int n  = nk >> 7;
    int k  = nk & 127;
    int widx = (l << 14) + (k << 7) + n;
    WTsum[i]  = (__bf16)Wsum[widx];
    WTprod[i] = (__bf16)Wprod[widx];
}

// ---------------------------------------------------------------------------
// emb prep: out[0] = emb (fp32)  AND  xbf = bf16(emb), one read of emb.
// ---------------------------------------------------------------------------
__global__ __launch_bounds__(256) void emb_prep(
    const float* __restrict__ emb, float* __restrict__ out0,
    __bf16* __restrict__ xbf, long long n4)
{
    long long i = (long long)blockIdx.x * 256 + threadIdx.x;
    if (i >= n4) return;
    float4 v = reinterpret_cast<const float4*>(emb)[i];
    reinterpret_cast<float4*>(out0)[i] = v;
    bf16x4 b;
    b[0] = (__bf16)v.x; b[1] = (__bf16)v.y;
    b[2] = (__bf16)v.z; b[3] = (__bf16)v.w;
    reinterpret_cast<bf16x4*>(xbf)[i] = b;
}

// ---------------------------------------------------------------------------
// CSR SpMM, bf16 gather payload: one 32-lane group per dst row; 8-deep MLP.
// ---------------------------------------------------------------------------
__global__ __launch_bounds__(256) void spmm_csr_bf16(
    const __bf16* __restrict__ x, const int* __restrict__ row_ptr,
    const int2* __restrict__ csr_sv, float* __restrict__ side, int N)
{
    int row  = blockIdx.x * 8 + (threadIdx.x >> 5);
    int lane = threadIdx.x & 31;
    if (row >= N) return;
    int start = row_ptr[row];
    int end   = row_ptr[row + 1];
    const __bf16* xl = x + lane * 4;
    float4 acc = make_float4(0.f, 0.f, 0.f, 0.f);
    int j = start;
    for (; j + 8 <= end; j += 8) {
        int2 sv0 = csr_sv[j + 0], sv1 = csr_sv[j + 1];
        int2 sv2 = csr_sv[j + 2], sv3 = csr_sv[j + 3];
        int2 sv4 = csr_sv[j + 4], sv5 = csr_sv[j + 5];
        int2 sv6 = csr_sv[j + 6], sv7 = csr_sv[j + 7];
        bf16x4 b0 = *reinterpret_cast<const bf16x4*>(xl + (long long)sv0.x * D_DIM);
        bf16x4 b1 = *reinterpret_cast<const bf16x4*>(xl + (long long)sv1.x * D_DIM);
        bf16x4 b2 = *reinterpret_cast<const bf16x4*>(xl + (long long)sv2.x * D_DIM);
        bf16x4 b3 = *reinterpret_cast<const bf16x4*>(xl + (long long)sv3.x * D_DIM);
        bf16x4 b4 = *reinterpret_cast<const bf16x4*>(xl + (long long)sv4.x * D_DIM);
        bf16x4 b5 = *reinterpret_cast<const bf16x4*>(xl + (long long)sv5.x * D_DIM);
        bf16x4 b6 = *reinterpret_cast<const bf16x4*>(xl + (long long)sv6.x * D_DIM);
        bf16x4 b7 = *reinterpret_cast<const bf16x4*>(xl + (long long)sv7.x * D_DIM);
        float v0 = __int_as_float(sv0.y), v1 = __int_as_float(sv1.y);
        float v2 = __int_as_float(sv2.y), v3 = __int_as_float(sv3.y);
        float v4 = __int_as_float(sv4.y), v5 = __int_as_float(sv5.y);
        float v6 = __int_as_float(sv6.y), v7 = __int_as_float(sv7.y);
        acc.x += v0 * (float)b0[0] + v1 * (float)b1[0] + v2 * (float)b2[0] + v3 * (float)b3[0];
        acc.y += v0 * (float)b0[1] + v1 * (float)b1[1] + v2 * (float)b2[1] + v3 * (float)b3[1];
        acc.z += v0 * (float)b0[2] + v1 * (float)b1[2] + v2 * (float)b2[2] + v3 * (float)b3[2];
        acc.w += v0 * (float)b0[3] + v1 * (float)b1[3] + v2 * (float)b2[3] + v3 * (float)b3[3];
        acc.x += v4 * (float)b4[0] + v5 * (float)b5[0] + v6 * (float)b6[0] + v7 * (float)b7[0];
        acc.y += v4 * (float)b4[1] + v5 * (float)b5[1] + v6 * (float)b6[1] + v7 * (float)b7[1];
        acc.z += v4 * (float)b4[2] + v5 * (float)b5[2] + v6 * (float)b6[2] + v7 * (float)b7[2];
        acc.w += v4 * (float)b4[3] + v5 * (float)b5[3] + v6 * (float)b6[3] + v7 * (float)b7[3];
    }
    for (; j + 4 <= end; j += 4) {
        int2 sv0 = csr_sv[j + 0], sv1 = csr_sv[j + 1];
        int2 sv2 = csr_sv[j + 2], sv3 = csr_sv[j + 3];
        bf16x4 b0 = *reinterpret_cast<const bf16x4*>(xl + (long long)sv0.x * D_DIM);
        bf16x4 b1 = *reinterpret_cast<const bf16x4*>(xl + (long long)sv1.x * D_DIM);
        bf16x4 b2 = *reinterpret_cast<const bf16x4*>(xl + (long long)sv2.x * D_DIM);
        bf16x4 b3 = *reinterpret_cast<const bf16x4*>(xl + (long long)sv3.x * D_DIM);
        float v0 = __int_as_float(sv0.y), v1 = __int_as_float(sv1.y);
        float v2 = __int_as_float(sv2.y), v3 = __int_as_float(sv3.y);
        acc.x += v0 * (float)b0[0] + v1 * (float)b1[0] + v2 * (float)b2[0] + v3 * (float)b3[0];
        acc.y += v0 * (float)b0[1] + v1 * (float)b1[1] + v2 * (float)b2[1] + v3 * (float)b3[1];
        acc.z += v0 * (float)b0[2] + v1 * (float)b1[2] + v2 * (float)b2[2] + v3 * (float)b3[2];
        acc.w += v0 * (float)b0[3] + v1 * (float)b1[3] + v2 * (float)b2[3] + v3 * (float)b3[3];
    }
    for (; j < end; ++j) {
        int2 sv = csr_sv[j];
        float v = __int_as_float(sv.y);
        bf16x4 b = *reinterpret_cast<const bf16x4*>(xl + (long long)sv.x * D_DIM);
        acc.x += v * (float)b[0];
        acc.y += v * (float)b[1];
        acc.z += v * (float)b[2];
        acc.w += v * (float)b[3];
    }
    *reinterpret_cast<float4*>(side + (long long)row * D_DIM + lane * 4) = acc;
}

// fp32 fallback CSR SpMM (used when mfma/bf16 workspace unavailable)
__global__ __launch_bounds__(256) void spmm_csr_f32(
    const float* __restrict__ x, const int* __restrict__ row_ptr,
    const int2* __restrict__ csr_sv, float* __restrict__ side, int N)
{
    int row  = blockIdx.x * 8 + (threadIdx.x >> 5);
    int lane = threadIdx.x & 31;
    if (row >= N) return;
    int start = row_ptr[row];
    int end   = row_ptr[row + 1];
    const float* xl = x + lane * 4;
    float4 acc = make_float4(0.f, 0.f, 0.f, 0.f);
    int j = start;
    for (; j + 4 <= end; j += 4) {
        int2 sv0 = csr_sv[j + 0], sv1 = csr_sv[j + 1];
        int2 sv2 = csr_sv[j + 2], sv3 = csr_sv[j + 3];
        const float4 x0 = *reinterpret_cast<const float4*>(xl + (long long)sv0.x * D_DIM);
        const float4 x1 = *reinterpret_cast<const float4*>(xl + (long long)sv1.x * D_DIM);
        const float4 x2 = *reinterpret_cast<const float4*>(xl + (long long)sv2.x * D_DIM);
        const float4 x3 = *reinterpret_cast<const float4*>(xl + (long long)sv3.x * D_DIM);
        float v0 = __int_as_float(sv0.y), v1 = __int_as_float(sv1.y);
        float v2 = __int_as_float(sv2.y), v3 = __int_as_float(sv3.y);
        acc.x += v0 * x0.x + v1 * x1.x + v2 * x2.x + v3 * x3.x;
        acc.y += v0 * x0.y + v1 * x1.y + v2 * x2.y + v3 * x3.y;
        acc.z += v0 * x0.z + v1 * x1.z + v2 * x2.z + v3 * x3.z;
        acc.w += v0 * x0.w + v1 * x1.w + v2 * x2.w + v3 * x3.w;
    }
    for (; j < end; ++j) {
        int2 sv = csr_sv[j];
        float v = __int_as_float(sv.y);
        const float4 xv = *reinterpret_cast<const float4*>(xl + (long long)sv.x * D_DIM);
        acc.x += v * xv.x;
        acc.y += v * xv.y;
        acc.z += v * xv.z;
        acc.w += v * xv.w;
    }
    *reinterpret_cast<float4*>(side + (long long)row * D_DIM + lane * 4) = acc;
}

// ---------------------------------------------------------------------------
// MFMA fused BiAggregator layer (unchanged from R2).
// ---------------------------------------------------------------------------
__global__ __launch_bounds__(256) void fused_layer_mfma(
    const float* __restrict__ ego, const float* __restrict__ side,
    const __bf16* __restrict__ WTsum, const float* __restrict__ bsum,
    const __bf16* __restrict__ WTprod, const float* __restrict__ bprod,
    float* __restrict__ ego_out,   // may be nullptr (last layer)
    float* __restrict__ norm_out,
    __bf16* __restrict__ nbf_out,  // may be nullptr (last layer)
    int N)
{
    __shared__ __bf16 zt[MROWS][ZPAD];
    __shared__ __bf16 mt[MROWS][ZPAD];

    const int tid  = threadIdx.x;
    const int row0 = blockIdx.x * MROWS;

    for (int idx = tid; idx < MROWS * 32; idx += 256) {
        int r = idx >> 5, q = idx & 31;
        int row = row0 + r;
        float4 e4 = make_float4(0.f, 0.f, 0.f, 0.f);
        float4 s4 = make_float4(0.f, 0.f, 0.f, 0.f);
        if (row < N) {
            e4 = *reinterpret_cast<const float4*>(ego  + (long long)row * D_DIM + q * 4);
            s4 = *reinterpret_cast<const float4*>(side + (long long)row * D_DIM + q * 4);
        }
        bf16x4 z4, m4;
        z4[0] = (__bf16)(e4.x + s4.x); z4[1] = (__bf16)(e4.y + s4.y);
        z4[2] = (__bf16)(e4.z + s4.z); z4[3] = (__bf16)(e4.w + s4.w);
        m4[0] = (__bf16)(e4.x * s4.x); m4[1] = (__bf16)(e4.y * s4.y);
        m4[2] = (__bf16)(e4.z * s4.z); m4[3] = (__bf16)(e4.w * s4.w);
        *reinterpret_cast<bf16x4*>(&zt[r][q * 4]) = z4;
        *reinterpret_cast<bf16x4*>(&mt[r][q * 4]) = m4;
    }
    __syncthreads();

    const int wave = tid >> 6;
    const int lane = tid & 63;
    const int ln   = lane & 15;
    const int quad = lane >> 4;
    const int mloc = wave * 16;

    f32x4 acc_s[8], acc_p[8];
#pragma unroll
    for (int nt = 0; nt < 8; ++nt) {
        acc_s[nt] = (f32x4){0.f, 0.f, 0.f, 0.f};
        acc_p[nt] = (f32x4){0.f, 0.f, 0.f, 0.f};
    }

#pragma unroll
    for (int ks = 0; ks < 4; ++ks) {
        const int k0 = ks * 32 + quad * 8;
        bf16x8 az = *reinterpret_cast<const bf16x8*>(&zt[mloc + ln][k0]);
        bf16x8 am = *reinterpret_cast<const bf16x8*>(&mt[mloc + ln][k0]);
#pragma unroll
        for (int nt = 0; nt < 8; ++nt) {
            const long long wofs = (long long)(nt * 16 + ln) * D_DIM + k0;
            bf16x8 bs = *reinterpret_cast<const bf16x8*>(WTsum  + wofs);
            bf16x8 bp = *reinterpret_cast<const bf16x8*>(WTprod + wofs);
            acc_s[nt] = __builtin_amdgcn_mfma_f32_16x16x32_bf16(az, bs, acc_s[nt], 0, 0, 0);
            acc_p[nt] = __builtin_amdgcn_mfma_f32_16x16x32_bf16(am, bp, acc_p[nt], 0, 0, 0);
        }
    }

    float bsv[8], bpv[8];
#pragma unroll
    for (int nt = 0; nt < 8; ++nt) {
        bsv[nt] = bsum[nt * 16 + ln];
        bpv[nt] = bprod[nt * 16 + ln];
    }
    float part[4] = {0.f, 0.f, 0.f, 0.f};
#pragma unroll
    for (int nt = 0; nt < 8; ++nt) {
#pragma unroll
        for (int r = 0; r < 4; ++r) {
            float sv = acc_s[nt][r] + bsv[nt];
            sv = sv > 0.f ? sv : 0.01f * sv;
            float pv = acc_p[nt][r] + bpv[nt];
            pv = pv > 0.f ? pv : 0.01f * pv;
            float e = sv + pv;
            acc_s[nt][r] = e;
            part[r] += e * e;
        }
    }
#pragma unroll
    for (int off = 1; off < 16; off <<= 1) {
#pragma unroll
        for (int r = 0; r < 4; ++r)
            part[r] += __shfl_xor(part[r], off, 16);
    }
#pragma unroll
    for (int r = 0; r < 4; ++r) {
        int row = row0 + mloc + quad * 4 + r;
        if (row >= N) continue;
        float inv = 1.0f / fmaxf(sqrtf(part[r]), 1e-12f);
        long long base = (long long)row * D_DIM + ln;
#pragma unroll
        for (int nt = 0; nt < 8; ++nt)
            norm_out[base + nt * 16] = acc_s[nt][r] * inv;
        if (nbf_out) {
#pragma unroll
            for (int nt = 0; nt < 8; ++nt)
                nbf_out[base + nt * 16] = (__bf16)(acc_s[nt][r] * inv);
        }
        if (ego_out) {
#pragma unroll
            for (int nt = 0; nt < 8; ++nt)
                ego_out[base + nt * 16] = acc_s[nt][r];
        }
    }
}

// ---------------------------------------------------------------------------
// fp32 fallback fused layer (R1 version)
// ---------------------------------------------------------------------------
__global__ __launch_bounds__(256) void fused_layer_f32(
    const float* __restrict__ ego, const float* __restrict__ side,
    const float* __restrict__ Wsum, const float* __restrict__ bsum,
    const float* __restrict__ Wprod, const float* __restrict__ bprod,
    float* __restrict__ ego_out, float* __restrict__ norm_out, int N)
{
    __shared__ float zt[ROWS][D_DIM];
    __shared__ float mt[ROWS][D_DIM];
    __shared__ float wsh[32][D_DIM];
    __shared__ float wph[32][D_DIM];

    const int tid  = threadIdx.x;
    const int row0 = blockIdx.x * ROWS;
    const int cg   = tid & 31;
    const int rg   = tid >> 5;

    for (int idx = tid; idx < ROWS * 32; idx += 256) {
        int r = idx >> 5, q = idx & 31;
        int row = row0 + r;
        float4 e4 = make_float4(0.f, 0.f, 0.f, 0.f);
        float4 s4 = make_float4(0.f, 0.f, 0.f, 0.f);
        if (row < N) {
            e4 = *reinterpret_cast<const float4*>(ego  + (long long)row * D_DIM + q * 4);
            s4 = *reinterpret_cast<const float4*>(side + (long long)row * D_DIM + q * 4);
        }
        float4 z4 = make_float4(e4.x + s4.x, e4.y + s4.y, e4.z + s4.z, e4.w + s4.w);
        float4 m4 = make_float4(e4.x * s4.x, e4.y * s4.y, e4.z * s4.z, e4.w * s4.w);
        *reinterpret_cast<float4*>(&zt[r][q * 4]) = z4;
        *reinterpret_cast<float4*>(&mt[r][q * 4]) = m4;
    }

    float acc_s[4][4], acc_p[4][4];
#pragma unroll
    for (int a = 0; a < 4; ++a)
#pragma unroll
        for (int b = 0; b < 4; ++b) { acc_s[a][b] = 0.f; acc_p[a][b] = 0.f; }

    for (int kc = 0; kc < D_DIM; kc += 32) {
        __syncthreads();
        for (int idx = tid; idx < 32 * 32; idx += 256) {
            int kk = idx >> 5, q = idx & 31;
            *reinterpret_cast<float4*>(&wsh[kk][q * 4]) =
                *reinterpret_cast<const float4*>(Wsum + (long long)(kc + kk) * D_DIM + q * 4);
            *reinterpret_cast<float4*>(&wph[kk][q * 4]) =
                *reinterpret_cast<const float4*>(Wprod + (long long)(kc + kk) * D_DIM + q * 4);
        }
        __syncthreads();
#pragma unroll 8
        for (int kk = 0; kk < 32; ++kk) {
            float4 w_s = *reinterpret_cast<const float4*>(&wsh[kk][cg * 4]);
            float4 w_p = *reinterpret_cast<const float4*>(&wph[kk][cg * 4]);
#pragma unroll
            for (int rr = 0; rr < 4; ++rr) {
                float z = zt[rg * 4 + rr][kc + kk];
                float m = mt[rg * 4 + rr][kc + kk];
                acc_s[rr][0] += z * w_s.x; acc_s[rr][1] += z * w_s.y;
                acc_s[rr][2] += z * w_s.z; acc_s[rr][3] += z * w_s.w;
                acc_p[rr][0] += m * w_p.x; acc_p[rr][1] += m * w_p.y;
                acc_p[rr][2] += m * w_p.z; acc_p[rr][3] += m * w_p.w;
            }
        }
    }

    const float4 bs = *reinterpret_cast<const float4*>(bsum  + cg * 4);
    const float4 bp = *reinterpret_cast<const float4*>(bprod + cg * 4);
    float ev[4][4];
    float part[4];
#pragma unroll
    for (int rr = 0; rr < 4; ++rr) {
        float bsv[4] = {bs.x, bs.y, bs.z, bs.w};
        float bpv[4] = {bp.x, bp.y, bp.z, bp.w};
        float acc = 0.f;
#pragma unroll
        for (int cc = 0; cc < 4; ++cc) {
            float sv = acc_s[rr][cc] + bsv[cc];
            sv = sv > 0.f ? sv : 0.01f * sv;
            float pv = acc_p[rr][cc] + bpv[cc];
            pv = pv > 0.f ? pv : 0.01f * pv;
            float e = sv + pv;
            ev[rr][cc] = e;
            acc += e * e;
        }
        part[rr] = acc;
    }
#pragma unroll
    for (int off = 1; off < 32; off <<= 1) {
#pragma unroll
        for (int rr = 0; rr < 4; ++rr)
            part[rr] += __shfl_xor(part[rr], off, 32);
    }
#pragma unroll
    for (int rr = 0; rr < 4; ++rr) {
        int row = row0 + rg * 4 + rr;
        if (row >= N) continue;
        float inv = 1.0f / fmaxf(sqrtf(part[rr]), 1e-12f);
        float4 o  = make_float4(ev[rr][0] * inv, ev[rr][1] * inv,
                                ev[rr][2] * inv, ev[rr][3] * inv);
        *reinterpret_cast<float4*>(norm_out + (long long)row * D_DIM + cg * 4) = o;
        if (ego_out) {
            float4 g = make_float4(ev[rr][0], ev[rr][1], ev[rr][2], ev[rr][3]);
            *reinterpret_cast<float4*>(ego_out + (long long)row * D_DIM + cg * 4) = g;
        }
    }
}

// ---------------------------------------------------------------------------
extern "C" void kernel_launch(void* const* d_in, const int* in_sizes, int n_in,
                              void* d_out, int out_size, void* d_ws, size_t ws_size,
                              hipStream_t stream)
{
    const float* emb   = (const float*)d_in[0];
    const int*   esrc  = (const int*)  d_in[1];
    const int*   edst  = (const int*)  d_in[2];
    const float* evalv = (const float*)d_in[3];
    const float* Wsum  = (const float*)d_in[4];
    const float* bsum  = (const float*)d_in[5];
    const float* Wprod = (const float*)d_in[6];
    const float* bprod = (const float*)d_in[7];
    float* out = (float*)d_out;

    const int D = 128;
    const int N = in_sizes[0] / D;
    const int E = in_sizes[1];
    const int L = in_sizes[5] / D;
    const size_t ND = (size_t)N * D;
    const int B = (N + 255) / 256;
    const int NB = (N + BROWS - 1) >> BSH;

    // workspace layout
    char* ws = (char*)d_ws;
    float* side    = (float*)ws;                 ws += ND * sizeof(float);
    float* ego_buf = (float*)ws;                 ws += ND * sizeof(float);
    int*   row_ptr  = (int*)ws;                  ws += (size_t)(N + 1) * sizeof(int);
    int*   row_fill = (int*)ws;                  ws += (size_t)N * sizeof(int);
    int*   blk_sums = (int*)ws;                  ws += (size_t)B * sizeof(int);
    ws = (char*)(((uintptr_t)ws + 15) & ~(uintptr_t)15);   // align for int2/vec
    int2*  csr_sv   = (int2*)ws;                 ws += (size_t)E * sizeof(int2);
    size_t csr_bytes = (size_t)(ws - (char*)d_ws);
    __bf16* WTsum  = (__bf16*)ws;                ws += (size_t)L * D * D * sizeof(__bf16);
    __bf16* WTprod = (__bf16*)ws;                ws += (size_t)L * D * D * sizeof(__bf16);
    __bf16* xbf    = (__bf16*)ws;                ws += ND * sizeof(__bf16);
    size_t mfma_bytes = (size_t)(ws - (char*)d_ws);
    int* bucket_cnt  = (int*)ws;                 ws += (size_t)(NB + 1) * sizeof(int);
    int* bucket_ptr  = (int*)ws;                 ws += (size_t)(NB + 1) * sizeof(int);
    int* bucket_fill = (int*)ws;                 ws += (size_t)(NB + 1) * sizeof(int);
    size_t bucket_bytes = (size_t)(ws - (char*)d_ws);
    // staging (E x int4) aliases side+ego_buf (dead until first SpMM)
    int* stage = (int*)side;

    const bool use_csr    = (ws_size >= csr_bytes);
    const bool use_mfma   = (ws_size >= mfma_bytes);
    const bool use_bucket = use_csr && (ws_size >= bucket_bytes) && (NB <= NB_MAX) &&
                            ((size_t)E * 16 <= 2 * ND * sizeof(float));

    // out[0] = embeddings (+ bf16 copy for SpMM when mfma path active)
    if (use_mfma) {
        long long n4 = (long long)(ND / 4);
        emb_prep<<<(int)((n4 + 255) / 256), 256, 0, stream>>>(emb, out, xbf, n4);
        int total = L * D * D;
        wt_convert<<<(total + 255) / 256, 256, 0, stream>>>(
            Wsum, Wprod, WTsum, WTprod, total);
    } else {
        hipMemcpyAsync(out, emb, ND * sizeof(float), hipMemcpyDeviceToDevice, stream);
    }

    if (use_bucket) {
        const int nblk = (E + CHUNK - 1) / CHUNK;
        hipMemsetAsync(bucket_cnt, 0, (size_t)NB * sizeof(int), stream);
        bucket_count<<<nblk, 256, 0, stream>>>(edst, bucket_cnt, E, NB);
        bucket_scan<<<1, 256, 0, stream>>>(bucket_cnt, bucket_ptr, bucket_fill, NB, E);
        bucket_scatter<<<nblk, 256, 0, stream>>>(
            esrc, edst, evalv, bucket_fill, stage, NB, E);
        bucket_finalize<<<NB, 256, 0, stream>>>(
            stage, bucket_ptr, row_ptr, csr_sv, N, E);
    } else if (use_csr) {
        hipMemsetAsync(row_fill, 0, (size_t)N * sizeof(int), stream);
        hist_kernel<<<(E + 255) / 256, 256, 0, stream>>>(edst, row_fill, E);
        scan_blocks<<<B, 256, 0, stream>>>(row_fill, row_ptr, blk_sums, N);
        scan_carry<<<1, 256, 0, stream>>>(blk_sums, B);
        scan_add<<<B, 256, 0, stream>>>(row_ptr, blk_sums, row_fill, N, E);
        scatter_kernel<<<(E + 255) / 256, 256, 0, stream>>>(
            esrc, edst, evalv, row_fill, csr_sv, E);
    }

    const float* ego     = emb;
    const float* spmm_in = emb;   // fp32 spmm input (fallback paths)
    for (int l = 0; l < L; ++l) {
        if (use_csr) {
            if (use_mfma) {
                spmm_csr_bf16<<<(N + 7) / 8, 256, 0, stream>>>(
                    xbf, row_ptr, csr_sv, side, N);
            } else {
                spmm_csr_f32<<<(N + 7) / 8, 256, 0, stream>>>(
                    spmm_in, row_ptr, csr_sv, side, N);
            }
        } else {
            hipMemsetAsync(side, 0, ND * sizeof(float), stream);
            long long total  = (long long)E * 32;
            long long blocks = (total + 255) / 256;
            spmm_atomic<<<(int)blocks, 256, 0, stream>>>(spmm_in, esrc, edst, evalv,
                                                         side, total);
        }

        float* norm_out = out + (size_t)(l + 1) * ND;
        float* ego_out  = (l + 1 < L) ? ego_buf : nullptr;
        if (use_mfma) {
            __bf16* nbf = (l + 1 < L) ? xbf : nullptr;  // next layer's SpMM input
            fused_layer_mfma<<<(N + MROWS - 1) / MROWS, 256, 0, stream>>>(
                ego, side,
                WTsum + (size_t)l * D * D, bsum + (size_t)l * D,
                WTprod + (size_t)l * D * D, bprod + (size_t)l * D,
                ego_out, norm_out, nbf, N);
        } else {
            fused_layer_f32<<<(N + ROWS - 1) / ROWS, 256, 0, stream>>>(
                ego, side,
                Wsum + (size_t)l * D * D, bsum + (size_t)l * D,
                Wprod + (size_t)l * D * D, bprod + (size_t)l * D,
                ego_out, norm_out, N);
        }

        ego     = ego_buf;
        spmm_in = norm_out;
    }
}

// Round 4
// 613.824 us; speedup vs baseline: 1.2651x; 1.0184x over previous
//
#include <hip/hip_runtime.h>

#define D_DIM 128
#define ROWS 32        // fp32 fallback tile
#define MROWS 64       // mfma kernel rows per block
#define ZPAD 136       // bf16 elems per LDS row: 272 B = 16B-aligned, low bank conflict
#define EPAD 132       // fp32 elems per LDS row in epilogue reuse (2-way max)

#define BSH 7                    // rows per bucket = 128
#define BROWS (1 << BSH)
#define NB_MAX 2048              // bucket-path guard: NB <= 2048
#define CHUNK 4096               // edges per block in bucket count/scatter

typedef __bf16 bf16x8 __attribute__((ext_vector_type(8)));
typedef __bf16 bf16x4 __attribute__((ext_vector_type(4)));
typedef float  f32x4  __attribute__((ext_vector_type(4)));

// ---------------------------------------------------------------------------
// Fallback SpMM (atomic): side[dst] += val * x[src]
// ---------------------------------------------------------------------------
__global__ __launch_bounds__(256) void spmm_atomic(
    const float* __restrict__ x, const int* __restrict__ src,
    const int* __restrict__ dst, const float* __restrict__ val,
    float* __restrict__ side, long long total)
{
    long long i = (long long)blockIdx.x * blockDim.x + threadIdx.x;
    if (i >= total) return;
    int e = (int)(i >> 5);
    int q = (int)(i & 31);
    int s = src[e];
    int d = dst[e];
    float v = val[e];
    const float4 xv = *reinterpret_cast<const float4*>(x + (long long)s * D_DIM + q * 4);
    float* o = side + (long long)d * D_DIM + q * 4;
    unsafeAtomicAdd(o + 0, v * xv.x);
    unsafeAtomicAdd(o + 1, v * xv.y);
    unsafeAtomicAdd(o + 2, v * xv.z);
    unsafeAtomicAdd(o + 3, v * xv.w);
}

// ---------------------------------------------------------------------------
// OLD CSR build (fallback): histogram -> exclusive scan -> scatter
// ---------------------------------------------------------------------------
__global__ __launch_bounds__(256) void hist_kernel(
    const int* __restrict__ dst, int* __restrict__ cnt, int E)
{
    int i = blockIdx.x * 256 + threadIdx.x;
    if (i < E) atomicAdd(&cnt[dst[i]], 1);
}

__global__ __launch_bounds__(256) void scan_blocks(
    const int* __restrict__ cnt, int* __restrict__ row_ptr,
    int* __restrict__ blk_sums, int N)
{
    __shared__ int sh[256];
    int i = blockIdx.x * 256 + threadIdx.x;
    int v = (i < N) ? cnt[i] : 0;
    sh[threadIdx.x] = v;
    __syncthreads();
#pragma unroll
    for (int off = 1; off < 256; off <<= 1) {
        int t = (threadIdx.x >= off) ? sh[threadIdx.x - off] : 0;
        __syncthreads();
        sh[threadIdx.x] += t;
        __syncthreads();
    }
    if (i < N) row_ptr[i] = sh[threadIdx.x] - v;
    if (threadIdx.x == 255) blk_sums[blockIdx.x] = sh[255];
}

__global__ __launch_bounds__(256) void scan_carry(int* __restrict__ blk, int B)
{
    __shared__ int sh[256];
    __shared__ int carry;
    if (threadIdx.x == 0) carry = 0;
    __syncthreads();
    for (int base = 0; base < B; base += 256) {
        int i = base + threadIdx.x;
        int v = (i < B) ? blk[i] : 0;
        sh[threadIdx.x] = v;
        __syncthreads();
#pragma unroll
        for (int off = 1; off < 256; off <<= 1) {
            int t = (threadIdx.x >= off) ? sh[threadIdx.x - off] : 0;
            __syncthreads();
            sh[threadIdx.x] += t;
            __syncthreads();
        }
        int excl = sh[threadIdx.x] - v + carry;
        if (i < B) blk[i] = excl;
        __syncthreads();
        if (threadIdx.x == 255) carry = carry + sh[255];
        __syncthreads();
    }
}

__global__ __launch_bounds__(256) void scan_add(
    int* __restrict__ row_ptr, const int* __restrict__ blk_sums,
    int* __restrict__ row_fill, int N, int E)
{
    int i = blockIdx.x * 256 + threadIdx.x;
    if (i < N) {
        int v = row_ptr[i] + blk_sums[i >> 8];
        row_ptr[i]  = v;
        row_fill[i] = v;
    }
    if (i == 0) row_ptr[N] = E;
}

__global__ __launch_bounds__(256) void scatter_kernel(
    const int* __restrict__ src, const int* __restrict__ dst,
    const float* __restrict__ val, int* __restrict__ row_fill,
    int2* __restrict__ csr_sv, int E)
{
    int e = blockIdx.x * 256 + threadIdx.x;
    if (e >= E) return;
    int d = dst[e];
    int pos = atomicAdd(&row_fill[d], 1);
    csr_sv[pos] = make_int2(src[e], __float_as_int(val[e]));
}

// ---------------------------------------------------------------------------
// Bucket-based CSR build: all per-row ranking atomics live in LDS.
// ---------------------------------------------------------------------------
__global__ __launch_bounds__(256) void bucket_count(
    const int* __restrict__ dst, int* __restrict__ bucket_cnt, int E, int NB)
{
    __shared__ int h[NB_MAX];
    for (int i = threadIdx.x; i < NB; i += 256) h[i] = 0;
    __syncthreads();
    int ebase = blockIdx.x * CHUNK;
    int ecnt  = min(CHUNK, E - ebase);
    for (int i = threadIdx.x; i < ecnt; i += 256)
        atomicAdd(&h[dst[ebase + i] >> BSH], 1);
    __syncthreads();
    for (int i = threadIdx.x; i < NB; i += 256)
        if (h[i]) atomicAdd(&bucket_cnt[i], h[i]);
}

__global__ __launch_bounds__(256) void bucket_scan(
    const int* __restrict__ bucket_cnt, int* __restrict__ bucket_ptr,
    int* __restrict__ bucket_fill, int NB, int E)
{
    __shared__ int sh[256];
    __shared__ int carry;
    if (threadIdx.x == 0) carry = 0;
    __syncthreads();
    for (int base = 0; base < NB; base += 256) {
        int i = base + threadIdx.x;
        int v = (i < NB) ? bucket_cnt[i] : 0;
        sh[threadIdx.x] = v;
        __syncthreads();
#pragma unroll
        for (int off = 1; off < 256; off <<= 1) {
            int t = (threadIdx.x >= off) ? sh[threadIdx.x - off] : 0;
            __syncthreads();
            sh[threadIdx.x] += t;
            __syncthreads();
        }
        if (i < NB) {
            int excl = sh[threadIdx.x] - v + carry;
            bucket_ptr[i]  = excl;
            bucket_fill[i] = excl;
        }
        __syncthreads();
        if (threadIdx.x == 255) carry = carry + sh[255];
        __syncthreads();
    }
    if (threadIdx.x == 0) bucket_ptr[NB] = E;
}

__global__ __launch_bounds__(256) void bucket_scatter(
    const int* __restrict__ src, const int* __restrict__ dst,
    const float* __restrict__ val, int* __restrict__ bucket_fill,
    int* __restrict__ stage,   // int4-strided: [E]{src, val, dst, pad}
    int NB, int E)
{
    __shared__ int hist[NB_MAX];   // counts, then reused as slot cursor
    __shared__ int excl[NB_MAX];
    __shared__ int gbase[NB_MAX];
    __shared__ int psum[256];
    __shared__ int s_src[CHUNK];
    __shared__ int s_val[CHUNK];
    __shared__ int s_dst[CHUNK];

    const int tid   = threadIdx.x;
    const int ebase = blockIdx.x * CHUNK;
    const int ecnt  = min(CHUNK, E - ebase);

    for (int i = tid; i < NB; i += 256) hist[i] = 0;
    __syncthreads();
    for (int i = tid; i < ecnt; i += 256)
        atomicAdd(&hist[dst[ebase + i] >> BSH], 1);
    __syncthreads();
    const int per = (NB + 255) / 256;        // <= 8
    const int t0  = tid * per;
    int tsum = 0;
    for (int k = 0; k < per; ++k) {
        int idx = t0 + k;
        tsum += (idx < NB) ? hist[idx] : 0;
    }
    psum[tid] = tsum;
    __syncthreads();
#pragma unroll
    for (int off = 1; off < 256; off <<= 1) {
        int t = (tid >= off) ? psum[tid - off] : 0;
        __syncthreads();
        psum[tid] += t;
        __syncthreads();
    }
    int run = psum[tid] - tsum;
    for (int k = 0; k < per; ++k) {
        int idx = t0 + k;
        if (idx < NB) { excl[idx] = run; run += hist[idx]; }
    }
    __syncthreads();
    for (int i = tid; i < NB; i += 256)
        gbase[i] = hist[i] ? atomicAdd(&bucket_fill[i], hist[i]) : 0;
    __syncthreads();
    for (int i = tid; i < NB; i += 256) hist[i] = excl[i];
    __syncthreads();
    for (int i = tid; i < ecnt; i += 256) {
        int d = dst[ebase + i];
        int slot = atomicAdd(&hist[d >> BSH], 1);
        s_src[slot] = src[ebase + i];
        s_val[slot] = __float_as_int(val[ebase + i]);
        s_dst[slot] = d;
    }
    __syncthreads();
    for (int i = tid; i < ecnt; i += 256) {
        int d   = s_dst[i];
        int bkt = d >> BSH;
        int gpos = gbase[bkt] + (i - excl[bkt]);
        *reinterpret_cast<int4*>(stage + 4 * (long long)gpos) =
            make_int4(s_src[i], s_val[i], d, 0);
    }
}

__global__ __launch_bounds__(256) void bucket_finalize(
    const int* __restrict__ stage, const int* __restrict__ bucket_ptr,
    int* __restrict__ row_ptr, int2* __restrict__ csr_sv, int N, int E)
{
    __shared__ int cnt[BROWS];
    __shared__ int rbase[BROWS];

    const int b   = blockIdx.x;
    const int tid = threadIdx.x;
    const int e0  = bucket_ptr[b];
    const int e1  = bucket_ptr[b + 1];
    const int r0  = b << BSH;
    const int nrows = min(BROWS, N - r0);

    if (tid < BROWS) cnt[tid] = 0;
    __syncthreads();
    for (int i = e0 + tid; i < e1; i += 256)
        atomicAdd(&cnt[stage[4 * (long long)i + 2] & (BROWS - 1)], 1);
    __syncthreads();
    if (tid < BROWS) rbase[tid] = cnt[tid];
    __syncthreads();
#pragma unroll
    for (int off = 1; off < BROWS; off <<= 1) {
        int t = 0;
        if (tid < BROWS && tid >= off) t = rbase[tid - off];
        __syncthreads();
        if (tid < BROWS) rbase[tid] += t;
        __syncthreads();
    }
    if (tid < BROWS) {
        int excl = e0 + rbase[tid] - cnt[tid];
        rbase[tid] = excl;
        if (tid < nrows) row_ptr[r0 + tid] = excl;
    }
    if (b == 0 && tid == 0) row_ptr[N] = E;
    __syncthreads();
    if (tid < BROWS) cnt[tid] = 0;     // reuse as rank cursor
    __syncthreads();
    for (int i = e0 + tid; i < e1; i += 256) {
        const int4 t = *reinterpret_cast<const int4*>(stage + 4 * (long long)i);
        int r = t.z & (BROWS - 1);
        int rank = atomicAdd(&cnt[r], 1);
        csr_sv[rbase[r] + rank] = make_int2(t.x, t.y);
    }
}

// ---------------------------------------------------------------------------
// W^T bf16 precompute: WT[l][n][k] = bf16(W[l][k][n]), both matrices.
// ---------------------------------------------------------------------------
__global__ __launch_bounds__(256) void wt_convert(
    const float* __restrict__ Wsum, const float* __restrict__ Wprod,
    __bf16* __restrict__ WTsum, __bf16* __restrict__ WTprod, int total)
{
    int i = blockIdx.x * 256 + threadIdx.x;
    if (i >= total) return;
    int l  = i >> 14;
    int nk = i & 16383;
    int n  = nk >> 7;
    int k  = nk & 127;
    int widx = (l << 14) + (k << 7) + n;
    WTsum[i]  = (__bf16)Wsum[widx];
    WTprod[i] = (__bf16)Wprod[widx];
}

// ---------------------------------------------------------------------------
// emb prep: out[0] = emb (fp32)  AND  xbf = bf16(emb), one read of emb.
// ---------------------------------------------------------------------------
__global__ __launch_bounds__(256) void emb_prep(
    const float* __restrict__ emb, float* __restrict__ out0,
    __bf16* __restrict__ xbf, long long n4)
{
    long long i = (long long)blockIdx.x * 256 + threadIdx.x;
    if (i >= n4) return;
    float4 v = reinterpret_cast<const float4*>(emb)[i];
    reinterpret_cast<float4*>(out0)[i] = v;
    bf16x4 b;
    b[0] = (__bf16)v.x; b[1] = (__bf16)v.y;
    b[2] = (__bf16)v.z; b[3] = (__bf16)v.w;
    reinterpret_cast<bf16x4*>(xbf)[i] = b;
}

// ---------------------------------------------------------------------------
// CSR SpMM, bf16 gather payload: one 32-lane group per dst row; 8-deep MLP.
// ---------------------------------------------------------------------------
__global__ __launch_bounds__(256) void spmm_csr_bf16(
    const __bf16* __restrict__ x, const int* __restrict__ row_ptr,
    const int2* __restrict__ csr_sv, float* __restrict__ side, int N)
{
    int row  = blockIdx.x * 8 + (threadIdx.x >> 5);
    int lane = threadIdx.x & 31;
    if (row >= N) return;
    int start = row_ptr[row];
    int end   = row_ptr[row + 1];
    const __bf16* xl = x + lane * 4;
    float4 acc = make_float4(0.f, 0.f, 0.f, 0.f);
    int j = start;
    for (; j + 8 <= end; j += 8) {
        int2 sv0 = csr_sv[j + 0], sv1 = csr_sv[j + 1];
        int2 sv2 = csr_sv[j + 2], sv3 = csr_sv[j + 3];
        int2 sv4 = csr_sv[j + 4], sv5 = csr_sv[j + 5];
        int2 sv6 = csr_sv[j + 6], sv7 = csr_sv[j + 7];
        bf16x4 b0 = *reinterpret_cast<const bf16x4*>(xl + (long long)sv0.x * D_DIM);
        bf16x4 b1 = *reinterpret_cast<const bf16x4*>(xl + (long long)sv1.x * D_DIM);
        bf16x4 b2 = *reinterpret_cast<const bf16x4*>(xl + (long long)sv2.x * D_DIM);
        bf16x4 b3 = *reinterpret_cast<const bf16x4*>(xl + (long long)sv3.x * D_DIM);
        bf16x4 b4 = *reinterpret_cast<const bf16x4*>(xl + (long long)sv4.x * D_DIM);
        bf16x4 b5 = *reinterpret_cast<const bf16x4*>(xl + (long long)sv5.x * D_DIM);
        bf16x4 b6 = *reinterpret_cast<const bf16x4*>(xl + (long long)sv6.x * D_DIM);
        bf16x4 b7 = *reinterpret_cast<const bf16x4*>(xl + (long long)sv7.x * D_DIM);
        float v0 = __int_as_float(sv0.y), v1 = __int_as_float(sv1.y);
        float v2 = __int_as_float(sv2.y), v3 = __int_as_float(sv3.y);
        float v4 = __int_as_float(sv4.y), v5 = __int_as_float(sv5.y);
        float v6 = __int_as_float(sv6.y), v7 = __int_as_float(sv7.y);
        acc.x += v0 * (float)b0[0] + v1 * (float)b1[0] + v2 * (float)b2[0] + v3 * (float)b3[0];
        acc.y += v0 * (float)b0[1] + v1 * (float)b1[1] + v2 * (float)b2[1] + v3 * (float)b3[1];
        acc.z += v0 * (float)b0[2] + v1 * (float)b1[2] + v2 * (float)b2[2] + v3 * (float)b3[2];
        acc.w += v0 * (float)b0[3] + v1 * (float)b1[3] + v2 * (float)b2[3] + v3 * (float)b3[3];
        acc.x += v4 * (float)b4[0] + v5 * (float)b5[0] + v6 * (float)b6[0] + v7 * (float)b7[0];
        acc.y += v4 * (float)b4[1] + v5 * (float)b5[1] + v6 * (float)b6[1] + v7 * (float)b7[1];
        acc.z += v4 * (float)b4[2] + v5 * (float)b5[2] + v6 * (float)b6[2] + v7 * (float)b7[2];
        acc.w += v4 * (float)b4[3] + v5 * (float)b5[3] + v6 * (float)b6[3] + v7 * (float)b7[3];
    }
    for (; j + 4 <= end; j += 4) {
        int2 sv0 = csr_sv[j + 0], sv1 = csr_sv[j + 1];
        int2 sv2 = csr_sv[j + 2], sv3 = csr_sv[j + 3];
        bf16x4 b0 = *reinterpret_cast<const bf16x4*>(xl + (long long)sv0.x * D_DIM);
        bf16x4 b1 = *reinterpret_cast<const bf16x4*>(xl + (long long)sv1.x * D_DIM);
        bf16x4 b2 = *reinterpret_cast<const bf16x4*>(xl + (long long)sv2.x * D_DIM);
        bf16x4 b3 = *reinterpret_cast<const bf16x4*>(xl + (long long)sv3.x * D_DIM);
        float v0 = __int_as_float(sv0.y), v1 = __int_as_float(sv1.y);
        float v2 = __int_as_float(sv2.y), v3 = __int_as_float(sv3.y);
        acc.x += v0 * (float)b0[0] + v1 * (float)b1[0] + v2 * (float)b2[0] + v3 * (float)b3[0];
        acc.y += v0 * (float)b0[1] + v1 * (float)b1[1] + v2 * (float)b2[1] + v3 * (float)b3[1];
        acc.z += v0 * (float)b0[2] + v1 * (float)b1[2] + v2 * (float)b2[2] + v3 * (float)b3[2];
        acc.w += v0 * (float)b0[3] + v1 * (float)b1[3] + v2 * (float)b2[3] + v3 * (float)b3[3];
    }
    for (; j < end; ++j) {
        int2 sv = csr_sv[j];
        float v = __int_as_float(sv.y);
        bf16x4 b = *reinterpret_cast<const bf16x4*>(xl + (long long)sv.x * D_DIM);
        acc.x += v * (float)b[0];
        acc.y += v * (float)b[1];
        acc.z += v * (float)b[2];
        acc.w += v * (float)b[3];
    }
    *reinterpret_cast<float4*>(side + (long long)row * D_DIM + lane * 4) = acc;
}

// fp32 fallback CSR SpMM (used when mfma/bf16 workspace unavailable)
__global__ __launch_bounds__(256) void spmm_csr_f32(
    const float* __restrict__ x, const int* __restrict__ row_ptr,
    const int2* __restrict__ csr_sv, float* __restrict__ side, int N)
{
    int row  = blockIdx.x * 8 + (threadIdx.x >> 5);
    int lane = threadIdx.x & 31;
    if (row >= N) return;
    int start = row_ptr[row];
    int end   = row_ptr[row + 1];
    const float* xl = x + lane * 4;
    float4 acc = make_float4(0.f, 0.f, 0.f, 0.f);
    int j = start;
    for (; j + 4 <= end; j += 4) {
        int2 sv0 = csr_sv[j + 0], sv1 = csr_sv[j + 1];
        int2 sv2 = csr_sv[j + 2], sv3 = csr_sv[j + 3];
        const float4 x0 = *reinterpret_cast<const float4*>(xl + (long long)sv0.x * D_DIM);
        const float4 x1 = *reinterpret_cast<const float4*>(xl + (long long)sv1.x * D_DIM);
        const float4 x2 = *reinterpret_cast<const float4*>(xl + (long long)sv2.x * D_DIM);
        const float4 x3 = *reinterpret_cast<const float4*>(xl + (long long)sv3.x * D_DIM);
        float v0 = __int_as_float(sv0.y), v1 = __int_as_float(sv1.y);
        float v2 = __int_as_float(sv2.y), v3 = __int_as_float(sv3.y);
        acc.x += v0 * x0.x + v1 * x1.x + v2 * x2.x + v3 * x3.x;
        acc.y += v0 * x0.y + v1 * x1.y + v2 * x2.y + v3 * x3.y;
        acc.z += v0 * x0.z + v1 * x1.z + v2 * x2.z + v3 * x3.z;
        acc.w += v0 * x0.w + v1 * x1.w + v2 * x2.w + v3 * x3.w;
    }
    for (; j < end; ++j) {
        int2 sv = csr_sv[j];
        float v = __int_as_float(sv.y);
        const float4 xv = *reinterpret_cast<const float4*>(xl + (long long)sv.x * D_DIM);
        acc.x += v * xv.x;
        acc.y += v * xv.y;
        acc.z += v * xv.z;
        acc.w += v * xv.w;
    }
    *reinterpret_cast<float4*>(side + (long long)row * D_DIM + lane * 4) = acc;
}

// ---------------------------------------------------------------------------
// MFMA fused BiAggregator layer, coalesced-store epilogue + nrm factoring.
//   ego input: if nrm_in != nullptr, ego[row] = ego_src[row] * nrm_in[row]
//   (reconstruct unnormalized ego from previous layer's normalized output).
//   Outputs: norm_out fp32 (coalesced float4), nbf_out bf16 (coalesced 8B),
//   nrm_out fp32 per-row norm (for next layer reconstruction). No ego_out:
//   saves 51.2 MB write + makes all wide stores row-major coalesced via an
//   LDS transpose reusing the staging buffer (float[64][EPAD] <= 34816 B).
// ---------------------------------------------------------------------------
__global__ __launch_bounds__(256) void fused_layer_mfma(
    const float* __restrict__ ego_src, const float* __restrict__ nrm_in,
    const float* __restrict__ side,
    const __bf16* __restrict__ WTsum, const float* __restrict__ bsum,
    const __bf16* __restrict__ WTprod, const float* __restrict__ bprod,
    float* __restrict__ norm_out,
    __bf16* __restrict__ nbf_out,  // may be nullptr (last layer)
    float* __restrict__ nrm_out,   // may be nullptr (last layer)
    int N)
{
    __shared__ __align__(16) char smem[MROWS * ZPAD * 2 * sizeof(__bf16)]; // 34816
    __shared__ float invs[MROWS];
    auto zt = reinterpret_cast<__bf16(*)[ZPAD]>(smem);
    auto mt = reinterpret_cast<__bf16(*)[ZPAD]>(smem + MROWS * ZPAD * sizeof(__bf16));
    auto et = reinterpret_cast<float(*)[EPAD]>(smem);   // epilogue reuse (33792 B)

    const int tid  = threadIdx.x;
    const int row0 = blockIdx.x * MROWS;

    // ---- stage z, m as bf16 (each thread 8 float4-pairs) ----
    for (int idx = tid; idx < MROWS * 32; idx += 256) {
        int r = idx >> 5, q = idx & 31;
        int row = row0 + r;
        float4 e4 = make_float4(0.f, 0.f, 0.f, 0.f);
        float4 s4 = make_float4(0.f, 0.f, 0.f, 0.f);
        if (row < N) {
            e4 = *reinterpret_cast<const float4*>(ego_src + (long long)row * D_DIM + q * 4);
            s4 = *reinterpret_cast<const float4*>(side    + (long long)row * D_DIM + q * 4);
            if (nrm_in) {
                float sc = nrm_in[row];
                e4.x *= sc; e4.y *= sc; e4.z *= sc; e4.w *= sc;
            }
        }
        bf16x4 z4, m4;
        z4[0] = (__bf16)(e4.x + s4.x); z4[1] = (__bf16)(e4.y + s4.y);
        z4[2] = (__bf16)(e4.z + s4.z); z4[3] = (__bf16)(e4.w + s4.w);
        m4[0] = (__bf16)(e4.x * s4.x); m4[1] = (__bf16)(e4.y * s4.y);
        m4[2] = (__bf16)(e4.z * s4.z); m4[3] = (__bf16)(e4.w * s4.w);
        *reinterpret_cast<bf16x4*>(&zt[r][q * 4]) = z4;
        *reinterpret_cast<bf16x4*>(&mt[r][q * 4]) = m4;
    }
    __syncthreads();

    const int wave = tid >> 6;
    const int lane = tid & 63;
    const int ln   = lane & 15;        // n within tile / m within A
    const int quad = lane >> 4;        // k-block selector (A/B), row-block (C)
    const int mloc = wave * 16;        // this wave's row base within block

    f32x4 acc_s[8], acc_p[8];
#pragma unroll
    for (int nt = 0; nt < 8; ++nt) {
        acc_s[nt] = (f32x4){0.f, 0.f, 0.f, 0.f};
        acc_p[nt] = (f32x4){0.f, 0.f, 0.f, 0.f};
    }

#pragma unroll
    for (int ks = 0; ks < 4; ++ks) {
        const int k0 = ks * 32 + quad * 8;
        bf16x8 az = *reinterpret_cast<const bf16x8*>(&zt[mloc + ln][k0]);
        bf16x8 am = *reinterpret_cast<const bf16x8*>(&mt[mloc + ln][k0]);
#pragma unroll
        for (int nt = 0; nt < 8; ++nt) {
            const long long wofs = (long long)(nt * 16 + ln) * D_DIM + k0;
            bf16x8 bs = *reinterpret_cast<const bf16x8*>(WTsum  + wofs);
            bf16x8 bp = *reinterpret_cast<const bf16x8*>(WTprod + wofs);
            acc_s[nt] = __builtin_amdgcn_mfma_f32_16x16x32_bf16(az, bs, acc_s[nt], 0, 0, 0);
            acc_p[nt] = __builtin_amdgcn_mfma_f32_16x16x32_bf16(am, bp, acc_p[nt], 0, 0, 0);
        }
    }

    // ---- epilogue phase 1: bias + lrelu + add, row L2-norm, LDS transpose ----
    float bsv[8], bpv[8];
#pragma unroll
    for (int nt = 0; nt < 8; ++nt) {
        bsv[nt] = bsum[nt * 16 + ln];
        bpv[nt] = bprod[nt * 16 + ln];
    }
    float part[4] = {0.f, 0.f, 0.f, 0.f};
#pragma unroll
    for (int nt = 0; nt < 8; ++nt) {
#pragma unroll
        for (int r = 0; r < 4; ++r) {
            float sv = acc_s[nt][r] + bsv[nt];
            sv = sv > 0.f ? sv : 0.01f * sv;
            float pv = acc_p[nt][r] + bpv[nt];
            pv = pv > 0.f ? pv : 0.01f * pv;
            float e = sv + pv;
            acc_s[nt][r] = e;           // reuse as e-store
            part[r] += e * e;
        }
    }
#pragma unroll
    for (int off = 1; off < 16; off <<= 1) {
#pragma unroll
        for (int r = 0; r < 4; ++r)
            part[r] += __shfl_xor(part[r], off, 16);
    }

    __syncthreads();   // all waves done reading zt/mt before et overwrite

#pragma unroll
    for (int r = 0; r < 4; ++r) {
        const int rl = mloc + quad * 4 + r;
        float nrmv = fmaxf(sqrtf(part[r]), 1e-12f);
        if (ln == 0) {
            invs[rl] = 1.0f / nrmv;
            int row = row0 + rl;
            if (nrm_out && row < N) nrm_out[row] = nrmv;
        }
#pragma unroll
        for (int nt = 0; nt < 8; ++nt)
            et[rl][nt * 16 + ln] = acc_s[nt][r];
    }
    __syncthreads();

    // ---- epilogue phase 2: coalesced row-major stores ----
    for (int idx = tid; idx < MROWS * 32; idx += 256) {
        int r = idx >> 5, q = idx & 31;
        int row = row0 + r;
        if (row >= N) continue;
        float inv = invs[r];
        float4 e4 = *reinterpret_cast<const float4*>(&et[r][q * 4]);
        float4 n4 = make_float4(e4.x * inv, e4.y * inv, e4.z * inv, e4.w * inv);
        *reinterpret_cast<float4*>(norm_out + (long long)row * D_DIM + q * 4) = n4;
        if (nbf_out) {
            bf16x4 b4;
            b4[0] = (__bf16)n4.x; b4[1] = (__bf16)n4.y;
            b4[2] = (__bf16)n4.z; b4[3] = (__bf16)n4.w;
            *reinterpret_cast<bf16x4*>(nbf_out + (long long)row * D_DIM + q * 4) = b4;
        }
    }
}

// ---------------------------------------------------------------------------
// fp32 fallback fused layer (R1 version)
// ---------------------------------------------------------------------------
__global__ __launch_bounds__(256) void fused_layer_f32(
    const float* __restrict__ ego, const float* __restrict__ side,
    const float* __restrict__ Wsum, const float* __restrict__ bsum,
    const float* __restrict__ Wprod, const float* __restrict__ bprod,
    float* __restrict__ ego_out, float* __restrict__ norm_out, int N)
{
    __shared__ float zt[ROWS][D_DIM];
    __shared__ float mt[ROWS][D_DIM];
    __shared__ float wsh[32][D_DIM];
    __shared__ float wph[32][D_DIM];

    const int tid  = threadIdx.x;
    const int row0 = blockIdx.x * ROWS;
    const int cg   = tid & 31;
    const int rg   = tid >> 5;

    for (int idx = tid; idx < ROWS * 32; idx += 256) {
        int r = idx >> 5, q = idx & 31;
        int row = row0 + r;
        float4 e4 = make_float4(0.f, 0.f, 0.f, 0.f);
        float4 s4 = make_float4(0.f, 0.f, 0.f, 0.f);
        if (row < N) {
            e4 = *reinterpret_cast<const float4*>(ego  + (long long)row * D_DIM + q * 4);
            s4 = *reinterpret_cast<const float4*>(side + (long long)row * D_DIM + q * 4);
        }
        float4 z4 = make_float4(e4.x + s4.x, e4.y + s4.y, e4.z + s4.z, e4.w + s4.w);
        float4 m4 = make_float4(e4.x * s4.x, e4.y * s4.y, e4.z * s4.z, e4.w * s4.w);
        *reinterpret_cast<float4*>(&zt[r][q * 4]) = z4;
        *reinterpret_cast<float4*>(&mt[r][q * 4]) = m4;
    }

    float acc_s[4][4], acc_p[4][4];
#pragma unroll
    for (int a = 0; a < 4; ++a)
#pragma unroll
        for (int b = 0; b < 4; ++b) { acc_s[a][b] = 0.f; acc_p[a][b] = 0.f; }

    for (int kc = 0; kc < D_DIM; kc += 32) {
        __syncthreads();
        for (int idx = tid; idx < 32 * 32; idx += 256) {
            int kk = idx >> 5, q = idx & 31;
            *reinterpret_cast<float4*>(&wsh[kk][q * 4]) =
                *reinterpret_cast<const float4*>(Wsum + (long long)(kc + kk) * D_DIM + q * 4);
            *reinterpret_cast<float4*>(&wph[kk][q * 4]) =
                *reinterpret_cast<const float4*>(Wprod + (long long)(kc + kk) * D_DIM + q * 4);
        }
        __syncthreads();
#pragma unroll 8
        for (int kk = 0; kk < 32; ++kk) {
            float4 w_s = *reinterpret_cast<const float4*>(&wsh[kk][cg * 4]);
            float4 w_p = *reinterpret_cast<const float4*>(&wph[kk][cg * 4]);
#pragma unroll
            for (int rr = 0; rr < 4; ++rr) {
                float z = zt[rg * 4 + rr][kc + kk];
                float m = mt[rg * 4 + rr][kc + kk];
                acc_s[rr][0] += z * w_s.x; acc_s[rr][1] += z * w_s.y;
                acc_s[rr][2] += z * w_s.z; acc_s[rr][3] += z * w_s.w;
                acc_p[rr][0] += m * w_p.x; acc_p[rr][1] += m * w_p.y;
                acc_p[rr][2] += m * w_p.z; acc_p[rr][3] += m * w_p.w;
            }
        }
    }

    const float4 bs = *reinterpret_cast<const float4*>(bsum  + cg * 4);
    const float4 bp = *reinterpret_cast<const float4*>(bprod + cg * 4);
    float ev[4][4];
    float part[4];
#pragma unroll
    for (int rr = 0; rr < 4; ++rr) {
        float bsv[4] = {bs.x, bs.y, bs.z, bs.w};
        float bpv[4] = {bp.x, bp.y, bp.z, bp.w};
        float acc = 0.f;
#pragma unroll
        for (int cc = 0; cc < 4; ++cc) {
            float sv = acc_s[rr][cc] + bsv[cc];
            sv = sv > 0.f ? sv : 0.01f * sv;
            float pv = acc_p[rr][cc] + bpv[cc];
            pv = pv > 0.f ? pv : 0.01f * pv;
            float e = sv + pv;
            ev[rr][cc] = e;
            acc += e * e;
        }
        part[rr] = acc;
    }
#pragma unroll
    for (int off = 1; off < 32; off <<= 1) {
#pragma unroll
        for (int rr = 0; rr < 4; ++rr)
            part[rr] += __shfl_xor(part[rr], off, 32);
    }
#pragma unroll
    for (int rr = 0; rr < 4; ++rr) {
        int row = row0 + rg * 4 + rr;
        if (row >= N) continue;
        float inv = 1.0f / fmaxf(sqrtf(part[rr]), 1e-12f);
        float4 o  = make_float4(ev[rr][0] * inv, ev[rr][1] * inv,
                                ev[rr][2] * inv, ev[rr][3] * inv);
        *reinterpret_cast<float4*>(norm_out + (long long)row * D_DIM + cg * 4) = o;
        if (ego_out) {
            float4 g = make_float4(ev[rr][0], ev[rr][1], ev[rr][2], ev[rr][3]);
            *reinterpret_cast<float4*>(ego_out + (long long)row * D_DIM + cg * 4) = g;
        }
    }
}

// ---------------------------------------------------------------------------
extern "C" void kernel_launch(void* const* d_in, const int* in_sizes, int n_in,
                              void* d_out, int out_size, void* d_ws, size_t ws_size,
                              hipStream_t stream)
{
    const float* emb   = (const float*)d_in[0];
    const int*   esrc  = (const int*)  d_in[1];
    const int*   edst  = (const int*)  d_in[2];
    const float* evalv = (const float*)d_in[3];
    const float* Wsum  = (const float*)d_in[4];
    const float* bsum  = (const float*)d_in[5];
    const float* Wprod = (const float*)d_in[6];
    const float* bprod = (const float*)d_in[7];
    float* out = (float*)d_out;

    const int D = 128;
    const int N = in_sizes[0] / D;
    const int E = in_sizes[1];
    const int L = in_sizes[5] / D;
    const size_t ND = (size_t)N * D;
    const int B = (N + 255) / 256;
    const int NB = (N + BROWS - 1) >> BSH;

    // workspace layout
    char* ws = (char*)d_ws;
    float* side    = (float*)ws;                 ws += ND * sizeof(float);
    float* ego_buf = (float*)ws;                 ws += ND * sizeof(float);
    int*   row_ptr  = (int*)ws;                  ws += (size_t)(N + 1) * sizeof(int);
    int*   row_fill = (int*)ws;                  ws += (size_t)N * sizeof(int);
    int*   blk_sums = (int*)ws;                  ws += (size_t)B * sizeof(int);
    ws = (char*)(((uintptr_t)ws + 15) & ~(uintptr_t)15);   // align for int2/vec
    int2*  csr_sv   = (int2*)ws;                 ws += (size_t)E * sizeof(int2);
    size_t csr_bytes = (size_t)(ws - (char*)d_ws);
    __bf16* WTsum  = (__bf16*)ws;                ws += (size_t)L * D * D * sizeof(__bf16);
    __bf16* WTprod = (__bf16*)ws;                ws += (size_t)L * D * D * sizeof(__bf16);
    __bf16* xbf    = (__bf16*)ws;                ws += ND * sizeof(__bf16);
    float*  nrm_buf = (float*)ws;                ws += (size_t)N * sizeof(float);
    size_t mfma_bytes = (size_t)(ws - (char*)d_ws);
    int* bucket_cnt  = (int*)ws;                 ws += (size_t)(NB + 1) * sizeof(int);
    int* bucket_ptr  = (int*)ws;                 ws += (size_t)(NB + 1) * sizeof(int);
    int* bucket_fill = (int*)ws;                 ws += (size_t)(NB + 1) * sizeof(int);
    size_t bucket_bytes = (size_t)(ws - (char*)d_ws);
    // staging (E x int4) aliases side+ego_buf (dead until first SpMM)
    int* stage = (int*)side;

    const bool use_csr    = (ws_size >= csr_bytes);
    const bool use_mfma   = (ws_size >= mfma_bytes);
    const bool use_bucket = use_csr && (ws_size >= bucket_bytes) && (NB <= NB_MAX) &&
                            ((size_t)E * 16 <= 2 * ND * sizeof(float));

    // out[0] = embeddings (+ bf16 copy for SpMM when mfma path active)
    if (use_mfma) {
        long long n4 = (long long)(ND / 4);
        emb_prep<<<(int)((n4 + 255) / 256), 256, 0, stream>>>(emb, out, xbf, n4);
        int total = L * D * D;
        wt_convert<<<(total + 255) / 256, 256, 0, stream>>>(
            Wsum, Wprod, WTsum, WTprod, total);
    } else {
        hipMemcpyAsync(out, emb, ND * sizeof(float), hipMemcpyDeviceToDevice, stream);
    }

    if (use_bucket) {
        const int nblk = (E + CHUNK - 1) / CHUNK;
        hipMemsetAsync(bucket_cnt, 0, (size_t)NB * sizeof(int), stream);
        bucket_count<<<nblk, 256, 0, stream>>>(edst, bucket_cnt, E, NB);
        bucket_scan<<<1, 256, 0, stream>>>(bucket_cnt, bucket_ptr, bucket_fill, NB, E);
        bucket_scatter<<<nblk, 256, 0, stream>>>(
            esrc, edst, evalv, bucket_fill, stage, NB, E);
        bucket_finalize<<<NB, 256, 0, stream>>>(
            stage, bucket_ptr, row_ptr, csr_sv, N, E);
    } else if (use_csr) {
        hipMemsetAsync(row_fill, 0, (size_t)N * sizeof(int), stream);
        hist_kernel<<<(E + 255) / 256, 256, 0, stream>>>(edst, row_fill, E);
        scan_blocks<<<B, 256, 0, stream>>>(row_fill, row_ptr, blk_sums, N);
        scan_carry<<<1, 256, 0, stream>>>(blk_sums, B);
        scan_add<<<B, 256, 0, stream>>>(row_ptr, blk_sums, row_fill, N, E);
        scatter_kernel<<<(E + 255) / 256, 256, 0, stream>>>(
            esrc, edst, evalv, row_fill, csr_sv, E);
    }

    const float* ego      = emb;       // fp32 ego source (or normalized w/ nrm)
    const float* nrm_prev = nullptr;   // per-row norm to reconstruct ego
    const float* spmm_in  = emb;       // fp32 spmm input (fallback paths)
    for (int l = 0; l < L; ++l) {
        if (use_csr) {
            if (use_mfma) {
                spmm_csr_bf16<<<(N + 7) / 8, 256, 0, stream>>>(
                    xbf, row_ptr, csr_sv, side, N);
            } else {
                spmm_csr_f32<<<(N + 7) / 8, 256, 0, stream>>>(
                    spmm_in, row_ptr, csr_sv, side, N);
            }
        } else {
            hipMemsetAsync(side, 0, ND * sizeof(float), stream);
            long long total  = (long long)E * 32;
            long long blocks = (total + 255) / 256;
            spmm_atomic<<<(int)blocks, 256, 0, stream>>>(spmm_in, esrc, edst, evalv,
                                                         side, total);
        }

        float* norm_out = out + (size_t)(l + 1) * ND;
        if (use_mfma) {
            const bool more = (l + 1 < L);
            __bf16* nbf  = more ? xbf : nullptr;      // next layer's SpMM input
            float*  nrmo = more ? nrm_buf : nullptr;  // next layer's ego scale
            fused_layer_mfma<<<(N + MROWS - 1) / MROWS, 256, 0, stream>>>(
                ego, nrm_prev, side,
                WTsum + (size_t)l * D * D, bsum + (size_t)l * D,
                WTprod + (size_t)l * D * D, bprod + (size_t)l * D,
                norm_out, nbf, nrmo, N);
            ego      = norm_out;
            nrm_prev = nrm_buf;
        } else {
            float* ego_out = (l + 1 < L) ? ego_buf : nullptr;
            fused_layer_f32<<<(N + ROWS - 1) / ROWS, 256, 0, stream>>>(
                ego, side,
                Wsum + (size_t)l * D * D, bsum + (size_t)l * D,
                Wprod + (size_t)l * D * D, bprod + (size_t)l * D,
                ego_out, norm_out, N);
            ego     = ego_buf;
            spmm_in = norm_out;
        }
    }
}

// Round 5
// 534.990 us; speedup vs baseline: 1.4515x; 1.1474x over previous
//
#include <hip/hip_runtime.h>

#define D_DIM 128
#define ROWS 32        // fp32 fallback tile
#define MROWS 64       // mfma kernel rows per block
#define ZPAD 136       // bf16 elems per LDS row: 272 B = 16B-aligned, low bank conflict
#define EPAD 132       // fp32 elems per LDS row in epilogue reuse (2-way max)

#define BSH 7                    // rows per bucket = 128
#define BROWS (1 << BSH)
#define NB_MAX 2048              // bucket-path guard: NB <= 2048
#define CHUNK 4096               // edges per block in bucket count/scatter

typedef __bf16 bf16x8 __attribute__((ext_vector_type(8)));
typedef __bf16 bf16x4 __attribute__((ext_vector_type(4)));
typedef float  f32x4  __attribute__((ext_vector_type(4)));

// ---------------------------------------------------------------------------
// Fallback SpMM (atomic): side[dst] += val * x[src]
// ---------------------------------------------------------------------------
__global__ __launch_bounds__(256) void spmm_atomic(
    const float* __restrict__ x, const int* __restrict__ src,
    const int* __restrict__ dst, const float* __restrict__ val,
    float* __restrict__ side, long long total)
{
    long long i = (long long)blockIdx.x * blockDim.x + threadIdx.x;
    if (i >= total) return;
    int e = (int)(i >> 5);
    int q = (int)(i & 31);
    int s = src[e];
    int d = dst[e];
    float v = val[e];
    const float4 xv = *reinterpret_cast<const float4*>(x + (long long)s * D_DIM + q * 4);
    float* o = side + (long long)d * D_DIM + q * 4;
    unsafeAtomicAdd(o + 0, v * xv.x);
    unsafeAtomicAdd(o + 1, v * xv.y);
    unsafeAtomicAdd(o + 2, v * xv.z);
    unsafeAtomicAdd(o + 3, v * xv.w);
}

// ---------------------------------------------------------------------------
// OLD CSR build (fallback): histogram -> exclusive scan -> scatter
// ---------------------------------------------------------------------------
__global__ __launch_bounds__(256) void hist_kernel(
    const int* __restrict__ dst, int* __restrict__ cnt, int E)
{
    int i = blockIdx.x * 256 + threadIdx.x;
    if (i < E) atomicAdd(&cnt[dst[i]], 1);
}

__global__ __launch_bounds__(256) void scan_blocks(
    const int* __restrict__ cnt, int* __restrict__ row_ptr,
    int* __restrict__ blk_sums, int N)
{
    __shared__ int sh[256];
    int i = blockIdx.x * 256 + threadIdx.x;
    int v = (i < N) ? cnt[i] : 0;
    sh[threadIdx.x] = v;
    __syncthreads();
#pragma unroll
    for (int off = 1; off < 256; off <<= 1) {
        int t = (threadIdx.x >= off) ? sh[threadIdx.x - off] : 0;
        __syncthreads();
        sh[threadIdx.x] += t;
        __syncthreads();
    }
    if (i < N) row_ptr[i] = sh[threadIdx.x] - v;
    if (threadIdx.x == 255) blk_sums[blockIdx.x] = sh[255];
}

__global__ __launch_bounds__(256) void scan_carry(int* __restrict__ blk, int B)
{
    __shared__ int sh[256];
    __shared__ int carry;
    if (threadIdx.x == 0) carry = 0;
    __syncthreads();
    for (int base = 0; base < B; base += 256) {
        int i = base + threadIdx.x;
        int v = (i < B) ? blk[i] : 0;
        sh[threadIdx.x] = v;
        __syncthreads();
#pragma unroll
        for (int off = 1; off < 256; off <<= 1) {
            int t = (threadIdx.x >= off) ? sh[threadIdx.x - off] : 0;
            __syncthreads();
            sh[threadIdx.x] += t;
            __syncthreads();
        }
        int excl = sh[threadIdx.x] - v + carry;
        if (i < B) blk[i] = excl;
        __syncthreads();
        if (threadIdx.x == 255) carry = carry + sh[255];
        __syncthreads();
    }
}

__global__ __launch_bounds__(256) void scan_add(
    int* __restrict__ row_ptr, const int* __restrict__ blk_sums,
    int* __restrict__ row_fill, int N, int E)
{
    int i = blockIdx.x * 256 + threadIdx.x;
    if (i < N) {
        int v = row_ptr[i] + blk_sums[i >> 8];
        row_ptr[i]  = v;
        row_fill[i] = v;
    }
    if (i == 0) row_ptr[N] = E;
}

__global__ __launch_bounds__(256) void scatter_kernel(
    const int* __restrict__ src, const int* __restrict__ dst,
    const float* __restrict__ val, int* __restrict__ row_fill,
    int2* __restrict__ csr_sv, int E)
{
    int e = blockIdx.x * 256 + threadIdx.x;
    if (e >= E) return;
    int d = dst[e];
    int pos = atomicAdd(&row_fill[d], 1);
    csr_sv[pos] = make_int2(src[e], __float_as_int(val[e]));
}

// ---------------------------------------------------------------------------
// Bucket-based CSR build: all per-row ranking atomics live in LDS.
// ---------------------------------------------------------------------------
__global__ __launch_bounds__(256) void bucket_count(
    const int* __restrict__ dst, int* __restrict__ bucket_cnt, int E, int NB)
{
    __shared__ int h[NB_MAX];
    for (int i = threadIdx.x; i < NB; i += 256) h[i] = 0;
    __syncthreads();
    int ebase = blockIdx.x * CHUNK;
    int ecnt  = min(CHUNK, E - ebase);
    for (int i = threadIdx.x; i < ecnt; i += 256)
        atomicAdd(&h[dst[ebase + i] >> BSH], 1);
    __syncthreads();
    for (int i = threadIdx.x; i < NB; i += 256)
        if (h[i]) atomicAdd(&bucket_cnt[i], h[i]);
}

__global__ __launch_bounds__(256) void bucket_scan(
    const int* __restrict__ bucket_cnt, int* __restrict__ bucket_ptr,
    int* __restrict__ bucket_fill, int NB, int E)
{
    __shared__ int sh[256];
    __shared__ int carry;
    if (threadIdx.x == 0) carry = 0;
    __syncthreads();
    for (int base = 0; base < NB; base += 256) {
        int i = base + threadIdx.x;
        int v = (i < NB) ? bucket_cnt[i] : 0;
        sh[threadIdx.x] = v;
        __syncthreads();
#pragma unroll
        for (int off = 1; off < 256; off <<= 1) {
            int t = (threadIdx.x >= off) ? sh[threadIdx.x - off] : 0;
            __syncthreads();
            sh[threadIdx.x] += t;
            __syncthreads();
        }
        if (i < NB) {
            int excl = sh[threadIdx.x] - v + carry;
            bucket_ptr[i]  = excl;
            bucket_fill[i] = excl;
        }
        __syncthreads();
        if (threadIdx.x == 255) carry = carry + sh[255];
        __syncthreads();
    }
    if (threadIdx.x == 0) bucket_ptr[NB] = E;
}

__global__ __launch_bounds__(256) void bucket_scatter(
    const int* __restrict__ src, const int* __restrict__ dst,
    const float* __restrict__ val, int* __restrict__ bucket_fill,
    int* __restrict__ stage,   // int4-strided: [E]{src, val, dst, pad}
    int NB, int E)
{
    __shared__ int hist[NB_MAX];   // counts, then reused as slot cursor
    __shared__ int excl[NB_MAX];
    __shared__ int gbase[NB_MAX];
    __shared__ int psum[256];
    __shared__ int s_src[CHUNK];
    __shared__ int s_val[CHUNK];
    __shared__ int s_dst[CHUNK];

    const int tid   = threadIdx.x;
    const int ebase = blockIdx.x * CHUNK;
    const int ecnt  = min(CHUNK, E - ebase);

    for (int i = tid; i < NB; i += 256) hist[i] = 0;
    __syncthreads();
    for (int i = tid; i < ecnt; i += 256)
        atomicAdd(&hist[dst[ebase + i] >> BSH], 1);
    __syncthreads();
    const int per = (NB + 255) / 256;        // <= 8
    const int t0  = tid * per;
    int tsum = 0;
    for (int k = 0; k < per; ++k) {
        int idx = t0 + k;
        tsum += (idx < NB) ? hist[idx] : 0;
    }
    psum[tid] = tsum;
    __syncthreads();
#pragma unroll
    for (int off = 1; off < 256; off <<= 1) {
        int t = (tid >= off) ? psum[tid - off] : 0;
        __syncthreads();
        psum[tid] += t;
        __syncthreads();
    }
    int run = psum[tid] - tsum;
    for (int k = 0; k < per; ++k) {
        int idx = t0 + k;
        if (idx < NB) { excl[idx] = run; run += hist[idx]; }
    }
    __syncthreads();
    for (int i = tid; i < NB; i += 256)
        gbase[i] = hist[i] ? atomicAdd(&bucket_fill[i], hist[i]) : 0;
    __syncthreads();
    for (int i = tid; i < NB; i += 256) hist[i] = excl[i];
    __syncthreads();
    for (int i = tid; i < ecnt; i += 256) {
        int d = dst[ebase + i];
        int slot = atomicAdd(&hist[d >> BSH], 1);
        s_src[slot] = src[ebase + i];
        s_val[slot] = __float_as_int(val[ebase + i]);
        s_dst[slot] = d;
    }
    __syncthreads();
    for (int i = tid; i < ecnt; i += 256) {
        int d   = s_dst[i];
        int bkt = d >> BSH;
        int gpos = gbase[bkt] + (i - excl[bkt]);
        *reinterpret_cast<int4*>(stage + 4 * (long long)gpos) =
            make_int4(s_src[i], s_val[i], d, 0);
    }
}

__global__ __launch_bounds__(256) void bucket_finalize(
    const int* __restrict__ stage, const int* __restrict__ bucket_ptr,
    int* __restrict__ row_ptr, int2* __restrict__ csr_sv, int N, int E)
{
    __shared__ int cnt[BROWS];
    __shared__ int rbase[BROWS];

    const int b   = blockIdx.x;
    const int tid = threadIdx.x;
    const int e0  = bucket_ptr[b];
    const int e1  = bucket_ptr[b + 1];
    const int r0  = b << BSH;
    const int nrows = min(BROWS, N - r0);

    if (tid < BROWS) cnt[tid] = 0;
    __syncthreads();
    for (int i = e0 + tid; i < e1; i += 256)
        atomicAdd(&cnt[stage[4 * (long long)i + 2] & (BROWS - 1)], 1);
    __syncthreads();
    if (tid < BROWS) rbase[tid] = cnt[tid];
    __syncthreads();
#pragma unroll
    for (int off = 1; off < BROWS; off <<= 1) {
        int t = 0;
        if (tid < BROWS && tid >= off) t = rbase[tid - off];
        __syncthreads();
        if (tid < BROWS) rbase[tid] += t;
        __syncthreads();
    }
    if (tid < BROWS) {
        int excl = e0 + rbase[tid] - cnt[tid];
        rbase[tid] = excl;
        if (tid < nrows) row_ptr[r0 + tid] = excl;
    }
    if (b == 0 && tid == 0) row_ptr[N] = E;
    __syncthreads();
    if (tid < BROWS) cnt[tid] = 0;     // reuse as rank cursor
    __syncthreads();
    for (int i = e0 + tid; i < e1; i += 256) {
        const int4 t = *reinterpret_cast<const int4*>(stage + 4 * (long long)i);
        int r = t.z & (BROWS - 1);
        int rank = atomicAdd(&cnt[r], 1);
        csr_sv[rbase[r] + rank] = make_int2(t.x, t.y);
    }
}

// ---------------------------------------------------------------------------
// W^T bf16 precompute: WT[l][n][k] = bf16(W[l][k][n]), both matrices.
// ---------------------------------------------------------------------------
__global__ __launch_bounds__(256) void wt_convert(
    const float* __restrict__ Wsum, const float* __restrict__ Wprod,
    __bf16* __restrict__ WTsum, __bf16* __restrict__ WTprod, int total)
{
    int i = blockIdx.x * 256 + threadIdx.x;
    if (i >= total) return;
    int l  = i >> 14;
    int nk = i & 16383;
    int n  = nk >> 7;
    int k  = nk & 127;
    int widx = (l << 14) + (k << 7) + n;
    WTsum[i]  = (__bf16)Wsum[widx];
    WTprod[i] = (__bf16)Wprod[widx];
}

// ---------------------------------------------------------------------------
// emb prep: out[0] = emb (fp32)  AND  xbf = bf16(emb), one read of emb.
// ---------------------------------------------------------------------------
__global__ __launch_bounds__(256) void emb_prep(
    const float* __restrict__ emb, float* __restrict__ out0,
    __bf16* __restrict__ xbf, long long n4)
{
    long long i = (long long)blockIdx.x * 256 + threadIdx.x;
    if (i >= n4) return;
    float4 v = reinterpret_cast<const float4*>(emb)[i];
    reinterpret_cast<float4*>(out0)[i] = v;
    bf16x4 b;
    b[0] = (__bf16)v.x; b[1] = (__bf16)v.y;
    b[2] = (__bf16)v.z; b[3] = (__bf16)v.w;
    reinterpret_cast<bf16x4*>(xbf)[i] = b;
}

// ---------------------------------------------------------------------------
// CSR SpMM, bf16 gather payload: one 32-lane group per dst row; 8-deep MLP.
// ---------------------------------------------------------------------------
__global__ __launch_bounds__(256) void spmm_csr_bf16(
    const __bf16* __restrict__ x, const int* __restrict__ row_ptr,
    const int2* __restrict__ csr_sv, float* __restrict__ side, int N)
{
    int row  = blockIdx.x * 8 + (threadIdx.x >> 5);
    int lane = threadIdx.x & 31;
    if (row >= N) return;
    int start = row_ptr[row];
    int end   = row_ptr[row + 1];
    const __bf16* xl = x + lane * 4;
    float4 acc = make_float4(0.f, 0.f, 0.f, 0.f);
    int j = start;
    for (; j + 8 <= end; j += 8) {
        int2 sv0 = csr_sv[j + 0], sv1 = csr_sv[j + 1];
        int2 sv2 = csr_sv[j + 2], sv3 = csr_sv[j + 3];
        int2 sv4 = csr_sv[j + 4], sv5 = csr_sv[j + 5];
        int2 sv6 = csr_sv[j + 6], sv7 = csr_sv[j + 7];
        bf16x4 b0 = *reinterpret_cast<const bf16x4*>(xl + (long long)sv0.x * D_DIM);
        bf16x4 b1 = *reinterpret_cast<const bf16x4*>(xl + (long long)sv1.x * D_DIM);
        bf16x4 b2 = *reinterpret_cast<const bf16x4*>(xl + (long long)sv2.x * D_DIM);
        bf16x4 b3 = *reinterpret_cast<const bf16x4*>(xl + (long long)sv3.x * D_DIM);
        bf16x4 b4 = *reinterpret_cast<const bf16x4*>(xl + (long long)sv4.x * D_DIM);
        bf16x4 b5 = *reinterpret_cast<const bf16x4*>(xl + (long long)sv5.x * D_DIM);
        bf16x4 b6 = *reinterpret_cast<const bf16x4*>(xl + (long long)sv6.x * D_DIM);
        bf16x4 b7 = *reinterpret_cast<const bf16x4*>(xl + (long long)sv7.x * D_DIM);
        float v0 = __int_as_float(sv0.y), v1 = __int_as_float(sv1.y);
        float v2 = __int_as_float(sv2.y), v3 = __int_as_float(sv3.y);
        float v4 = __int_as_float(sv4.y), v5 = __int_as_float(sv5.y);
        float v6 = __int_as_float(sv6.y), v7 = __int_as_float(sv7.y);
        acc.x += v0 * (float)b0[0] + v1 * (float)b1[0] + v2 * (float)b2[0] + v3 * (float)b3[0];
        acc.y += v0 * (float)b0[1] + v1 * (float)b1[1] + v2 * (float)b2[1] + v3 * (float)b3[1];
        acc.z += v0 * (float)b0[2] + v1 * (float)b1[2] + v2 * (float)b2[2] + v3 * (float)b3[2];
        acc.w += v0 * (float)b0[3] + v1 * (float)b1[3] + v2 * (float)b2[3] + v3 * (float)b3[3];
        acc.x += v4 * (float)b4[0] + v5 * (float)b5[0] + v6 * (float)b6[0] + v7 * (float)b7[0];
        acc.y += v4 * (float)b4[1] + v5 * (float)b5[1] + v6 * (float)b6[1] + v7 * (float)b7[1];
        acc.z += v4 * (float)b4[2] + v5 * (float)b5[2] + v6 * (float)b6[2] + v7 * (float)b7[2];
        acc.w += v4 * (float)b4[3] + v5 * (float)b5[3] + v6 * (float)b6[3] + v7 * (float)b7[3];
    }
    for (; j + 4 <= end; j += 4) {
        int2 sv0 = csr_sv[j + 0], sv1 = csr_sv[j + 1];
        int2 sv2 = csr_sv[j + 2], sv3 = csr_sv[j + 3];
        bf16x4 b0 = *reinterpret_cast<const bf16x4*>(xl + (long long)sv0.x * D_DIM);
        bf16x4 b1 = *reinterpret_cast<const bf16x4*>(xl + (long long)sv1.x * D_DIM);
        bf16x4 b2 = *reinterpret_cast<const bf16x4*>(xl + (long long)sv2.x * D_DIM);
        bf16x4 b3 = *reinterpret_cast<const bf16x4*>(xl + (long long)sv3.x * D_DIM);
        float v0 = __int_as_float(sv0.y), v1 = __int_as_float(sv1.y);
        float v2 = __int_as_float(sv2.y), v3 = __int_as_float(sv3.y);
        acc.x += v0 * (float)b0[0] + v1 * (float)b1[0] + v2 * (float)b2[0] + v3 * (float)b3[0];
        acc.y += v0 * (float)b0[1] + v1 * (float)b1[1] + v2 * (float)b2[1] + v3 * (float)b3[1];
        acc.z += v0 * (float)b0[2] + v1 * (float)b1[2] + v2 * (float)b2[2] + v3 * (float)b3[2];
        acc.w += v0 * (float)b0[3] + v1 * (float)b1[3] + v2 * (float)b2[3] + v3 * (float)b3[3];
    }
    for (; j < end; ++j) {
        int2 sv = csr_sv[j];
        float v = __int_as_float(sv.y);
        bf16x4 b = *reinterpret_cast<const bf16x4*>(xl + (long long)sv.x * D_DIM);
        acc.x += v * (float)b[0];
        acc.y += v * (float)b[1];
        acc.z += v * (float)b[2];
        acc.w += v * (float)b[3];
    }
    *reinterpret_cast<float4*>(side + (long long)row * D_DIM + lane * 4) = acc;
}

// fp32 fallback CSR SpMM (used when mfma/bf16 workspace unavailable)
__global__ __launch_bounds__(256) void spmm_csr_f32(
    const float* __restrict__ x, const int* __restrict__ row_ptr,
    const int2* __restrict__ csr_sv, float* __restrict__ side, int N)
{
    int row  = blockIdx.x * 8 + (threadIdx.x >> 5);
    int lane = threadIdx.x & 31;
    if (row >= N) return;
    int start = row_ptr[row];
    int end   = row_ptr[row + 1];
    const float* xl = x + lane * 4;
    float4 acc = make_float4(0.f, 0.f, 0.f, 0.f);
    int j = start;
    for (; j + 4 <= end; j += 4) {
        int2 sv0 = csr_sv[j + 0], sv1 = csr_sv[j + 1];
        int2 sv2 = csr_sv[j + 2], sv3 = csr_sv[j + 3];
        const float4 x0 = *reinterpret_cast<const float4*>(xl + (long long)sv0.x * D_DIM);
        const float4 x1 = *reinterpret_cast<const float4*>(xl + (long long)sv1.x * D_DIM);
        const float4 x2 = *reinterpret_cast<const float4*>(xl + (long long)sv2.x * D_DIM);
        const float4 x3 = *reinterpret_cast<const float4*>(xl + (long long)sv3.x * D_DIM);
        float v0 = __int_as_float(sv0.y), v1 = __int_as_float(sv1.y);
        float v2 = __int_as_float(sv2.y), v3 = __int_as_float(sv3.y);
        acc.x += v0 * x0.x + v1 * x1.x + v2 * x2.x + v3 * x3.x;
        acc.y += v0 * x0.y + v1 * x1.y + v2 * x2.y + v3 * x3.y;
        acc.z += v0 * x0.z + v1 * x1.z + v2 * x2.z + v3 * x3.z;
        acc.w += v0 * x0.w + v1 * x1.w + v2 * x2.w + v3 * x3.w;
    }
    for (; j < end; ++j) {
        int2 sv = csr_sv[j];
        float v = __int_as_float(sv.y);
        const float4 xv = *reinterpret_cast<const float4*>(xl + (long long)sv.x * D_DIM);
        acc.x += v * xv.x;
        acc.y += v * xv.y;
        acc.z += v * xv.z;
        acc.w += v * xv.w;
    }
    *reinterpret_cast<float4*>(side + (long long)row * D_DIM + lane * 4) = acc;
}

// ---------------------------------------------------------------------------
// MFMA fused BiAggregator layer, v3: 512 thr / 8 waves, wave-per-column-tile.
//   Each wave owns one 16-col tile (nt = wave), hoists its B-fragments
//   (4 ks x 2 matrices, 8 x bf16x8 = 64 regs) into registers ONCE, then
//   sweeps all 4 row-groups. Global loads in the MFMA loop: 0 (was 256/blk).
//   Row L2-norm reduced across waves via rowsq[64][9] LDS (pad 9: no bank
//   clash on row-stride-4 writes). Coalesced phase-2 stores via et reuse.
// ---------------------------------------------------------------------------
__global__ __launch_bounds__(512) void fused_layer_mfma(
    const float* __restrict__ ego_src, const float* __restrict__ nrm_in,
    const float* __restrict__ side,
    const __bf16* __restrict__ WTsum, const float* __restrict__ bsum,
    const __bf16* __restrict__ WTprod, const float* __restrict__ bprod,
    float* __restrict__ norm_out,
    __bf16* __restrict__ nbf_out,  // may be nullptr (last layer)
    float* __restrict__ nrm_out,   // may be nullptr (last layer)
    int N)
{
    __shared__ __align__(16) char smem[MROWS * ZPAD * 2 * sizeof(__bf16)]; // 34816
    __shared__ float rowsq[MROWS][9];
    auto zt = reinterpret_cast<__bf16(*)[ZPAD]>(smem);
    auto mt = reinterpret_cast<__bf16(*)[ZPAD]>(smem + MROWS * ZPAD * sizeof(__bf16));
    auto et = reinterpret_cast<float(*)[EPAD]>(smem);   // epilogue reuse (33792 B)

    const int tid  = threadIdx.x;
    const int row0 = blockIdx.x * MROWS;

    // ---- stage z, m as bf16 ----
    for (int idx = tid; idx < MROWS * 32; idx += 512) {
        int r = idx >> 5, q = idx & 31;
        int row = row0 + r;
        float4 e4 = make_float4(0.f, 0.f, 0.f, 0.f);
        float4 s4 = make_float4(0.f, 0.f, 0.f, 0.f);
        if (row < N) {
            e4 = *reinterpret_cast<const float4*>(ego_src + (long long)row * D_DIM + q * 4);
            s4 = *reinterpret_cast<const float4*>(side    + (long long)row * D_DIM + q * 4);
            if (nrm_in) {
                float sc = nrm_in[row];
                e4.x *= sc; e4.y *= sc; e4.z *= sc; e4.w *= sc;
            }
        }
        bf16x4 z4, m4;
        z4[0] = (__bf16)(e4.x + s4.x); z4[1] = (__bf16)(e4.y + s4.y);
        z4[2] = (__bf16)(e4.z + s4.z); z4[3] = (__bf16)(e4.w + s4.w);
        m4[0] = (__bf16)(e4.x * s4.x); m4[1] = (__bf16)(e4.y * s4.y);
        m4[2] = (__bf16)(e4.z * s4.z); m4[3] = (__bf16)(e4.w * s4.w);
        *reinterpret_cast<bf16x4*>(&zt[r][q * 4]) = z4;
        *reinterpret_cast<bf16x4*>(&mt[r][q * 4]) = m4;
    }

    const int wave = tid >> 6;         // = nt, column tile (0..7)
    const int lane = tid & 63;
    const int ln   = lane & 15;        // n within tile / m within A
    const int quad = lane >> 4;        // k-block selector (A/B), row-block (C)

    // ---- B fragments hoisted to registers (global/L2, overlap w/ staging) ----
    bf16x8 bs[4], bp[4];
#pragma unroll
    for (int ks = 0; ks < 4; ++ks) {
        const long long wofs = (long long)(wave * 16 + ln) * D_DIM + ks * 32 + quad * 8;
        bs[ks] = *reinterpret_cast<const bf16x8*>(WTsum  + wofs);
        bp[ks] = *reinterpret_cast<const bf16x8*>(WTprod + wofs);
    }

    __syncthreads();

    f32x4 acc_s[4], acc_p[4];
#pragma unroll
    for (int rg = 0; rg < 4; ++rg) {
        acc_s[rg] = (f32x4){0.f, 0.f, 0.f, 0.f};
        acc_p[rg] = (f32x4){0.f, 0.f, 0.f, 0.f};
    }

#pragma unroll
    for (int rg = 0; rg < 4; ++rg) {
#pragma unroll
        for (int ks = 0; ks < 4; ++ks) {
            const int k0 = ks * 32 + quad * 8;
            bf16x8 az = *reinterpret_cast<const bf16x8*>(&zt[rg * 16 + ln][k0]);
            bf16x8 am = *reinterpret_cast<const bf16x8*>(&mt[rg * 16 + ln][k0]);
            acc_s[rg] = __builtin_amdgcn_mfma_f32_16x16x32_bf16(az, bs[ks], acc_s[rg], 0, 0, 0);
            acc_p[rg] = __builtin_amdgcn_mfma_f32_16x16x32_bf16(am, bp[ks], acc_p[rg], 0, 0, 0);
        }
    }

    // ---- epilogue phase 1: bias + lrelu + add, per-wave row partial norms ----
    const float bsv = bsum[wave * 16 + ln];
    const float bpv = bprod[wave * 16 + ln];
#pragma unroll
    for (int rg = 0; rg < 4; ++rg) {
#pragma unroll
        for (int r = 0; r < 4; ++r) {
            float sv = acc_s[rg][r] + bsv;
            sv = sv > 0.f ? sv : 0.01f * sv;
            float pv = acc_p[rg][r] + bpv;
            pv = pv > 0.f ? pv : 0.01f * pv;
            float e = sv + pv;
            acc_s[rg][r] = e;           // reuse as e-store
            float sq = e * e;
#pragma unroll
            for (int off = 1; off < 16; off <<= 1)
                sq += __shfl_xor(sq, off, 16);
            if (ln == 0)
                rowsq[rg * 16 + quad * 4 + r][wave] = sq;
        }
    }

    __syncthreads();   // all waves done reading zt/mt; rowsq complete

    // ---- LDS transpose: e into row-major et ----
#pragma unroll
    for (int rg = 0; rg < 4; ++rg)
#pragma unroll
        for (int r = 0; r < 4; ++r)
            et[rg * 16 + quad * 4 + r][wave * 16 + ln] = acc_s[rg][r];
    __syncthreads();

    // ---- epilogue phase 2: coalesced row-major stores ----
    for (int idx = tid; idx < MROWS * 32; idx += 512) {
        int r = idx >> 5, q = idx & 31;
        int row = row0 + r;
        if (row >= N) continue;
        float s = 0.f;
#pragma unroll
        for (int j = 0; j < 8; ++j) s += rowsq[r][j];
        float nrmv = fmaxf(sqrtf(s), 1e-12f);
        float inv  = 1.0f / nrmv;
        if (q == 0 && nrm_out) nrm_out[row] = nrmv;
        float4 e4 = *reinterpret_cast<const float4*>(&et[r][q * 4]);
        float4 n4 = make_float4(e4.x * inv, e4.y * inv, e4.z * inv, e4.w * inv);
        *reinterpret_cast<float4*>(norm_out + (long long)row * D_DIM + q * 4) = n4;
        if (nbf_out) {
            bf16x4 b4;
            b4[0] = (__bf16)n4.x; b4[1] = (__bf16)n4.y;
            b4[2] = (__bf16)n4.z; b4[3] = (__bf16)n4.w;
            *reinterpret_cast<bf16x4*>(nbf_out + (long long)row * D_DIM + q * 4) = b4;
        }
    }
}

// ---------------------------------------------------------------------------
// fp32 fallback fused layer (R1 version)
// ---------------------------------------------------------------------------
__global__ __launch_bounds__(256) void fused_layer_f32(
    const float* __restrict__ ego, const float* __restrict__ side,
    const float* __restrict__ Wsum, const float* __restrict__ bsum,
    const float* __restrict__ Wprod, const float* __restrict__ bprod,
    float* __restrict__ ego_out, float* __restrict__ norm_out, int N)
{
    __shared__ float zt[ROWS][D_DIM];
    __shared__ float mt[ROWS][D_DIM];
    __shared__ float wsh[32][D_DIM];
    __shared__ float wph[32][D_DIM];

    const int tid  = threadIdx.x;
    const int row0 = blockIdx.x * ROWS;
    const int cg   = tid & 31;
    const int rg   = tid >> 5;

    for (int idx = tid; idx < ROWS * 32; idx += 256) {
        int r = idx >> 5, q = idx & 31;
        int row = row0 + r;
        float4 e4 = make_float4(0.f, 0.f, 0.f, 0.f);
        float4 s4 = make_float4(0.f, 0.f, 0.f, 0.f);
        if (row < N) {
            e4 = *reinterpret_cast<const float4*>(ego  + (long long)row * D_DIM + q * 4);
            s4 = *reinterpret_cast<const float4*>(side + (long long)row * D_DIM + q * 4);
        }
        float4 z4 = make_float4(e4.x + s4.x, e4.y + s4.y, e4.z + s4.z, e4.w + s4.w);
        float4 m4 = make_float4(e4.x * s4.x, e4.y * s4.y, e4.z * s4.z, e4.w * s4.w);
        *reinterpret_cast<float4*>(&zt[r][q * 4]) = z4;
        *reinterpret_cast<float4*>(&mt[r][q * 4]) = m4;
    }

    float acc_s[4][4], acc_p[4][4];
#pragma unroll
    for (int a = 0; a < 4; ++a)
#pragma unroll
        for (int b = 0; b < 4; ++b) { acc_s[a][b] = 0.f; acc_p[a][b] = 0.f; }

    for (int kc = 0; kc < D_DIM; kc += 32) {
        __syncthreads();
        for (int idx = tid; idx < 32 * 32; idx += 256) {
            int kk = idx >> 5, q = idx & 31;
            *reinterpret_cast<float4*>(&wsh[kk][q * 4]) =
                *reinterpret_cast<const float4*>(Wsum + (long long)(kc + kk) * D_DIM + q * 4);
            *reinterpret_cast<float4*>(&wph[kk][q * 4]) =
                *reinterpret_cast<const float4*>(Wprod + (long long)(kc + kk) * D_DIM + q * 4);
        }
        __syncthreads();
#pragma unroll 8
        for (int kk = 0; kk < 32; ++kk) {
            float4 w_s = *reinterpret_cast<const float4*>(&wsh[kk][cg * 4]);
            float4 w_p = *reinterpret_cast<const float4*>(&wph[kk][cg * 4]);
#pragma unroll
            for (int rr = 0; rr < 4; ++rr) {
                float z = zt[rg * 4 + rr][kc + kk];
                float m = mt[rg * 4 + rr][kc + kk];
                acc_s[rr][0] += z * w_s.x; acc_s[rr][1] += z * w_s.y;
                acc_s[rr][2] += z * w_s.z; acc_s[rr][3] += z * w_s.w;
                acc_p[rr][0] += m * w_p.x; acc_p[rr][1] += m * w_p.y;
                acc_p[rr][2] += m * w_p.z; acc_p[rr][3] += m * w_p.w;
            }
        }
    }

    const float4 bs = *reinterpret_cast<const float4*>(bsum  + cg * 4);
    const float4 bp = *reinterpret_cast<const float4*>(bprod + cg * 4);
    float ev[4][4];
    float part[4];
#pragma unroll
    for (int rr = 0; rr < 4; ++rr) {
        float bsv[4] = {bs.x, bs.y, bs.z, bs.w};
        float bpv[4] = {bp.x, bp.y, bp.z, bp.w};
        float acc = 0.f;
#pragma unroll
        for (int cc = 0; cc < 4; ++cc) {
            float sv = acc_s[rr][cc] + bsv[cc];
            sv = sv > 0.f ? sv : 0.01f * sv;
            float pv = acc_p[rr][cc] + bpv[cc];
            pv = pv > 0.f ? pv : 0.01f * pv;
            float e = sv + pv;
            ev[rr][cc] = e;
            acc += e * e;
        }
        part[rr] = acc;
    }
#pragma unroll
    for (int off = 1; off < 32; off <<= 1) {
#pragma unroll
        for (int rr = 0; rr < 4; ++rr)
            part[rr] += __shfl_xor(part[rr], off, 32);
    }
#pragma unroll
    for (int rr = 0; rr < 4; ++rr) {
        int row = row0 + rg * 4 + rr;
        if (row >= N) continue;
        float inv = 1.0f / fmaxf(sqrtf(part[rr]), 1e-12f);
        float4 o  = make_float4(ev[rr][0] * inv, ev[rr][1] * inv,
                                ev[rr][2] * inv, ev[rr][3] * inv);
        *reinterpret_cast<float4*>(norm_out + (long long)row * D_DIM + cg * 4) = o;
        if (ego_out) {
            float4 g = make_float4(ev[rr][0], ev[rr][1], ev[rr][2], ev[rr][3]);
            *reinterpret_cast<float4*>(ego_out + (long long)row * D_DIM + cg * 4) = g;
        }
    }
}

// ---------------------------------------------------------------------------
extern "C" void kernel_launch(void* const* d_in, const int* in_sizes, int n_in,
                              void* d_out, int out_size, void* d_ws, size_t ws_size,
                              hipStream_t stream)
{
    const float* emb   = (const float*)d_in[0];
    const int*   esrc  = (const int*)  d_in[1];
    const int*   edst  = (const int*)  d_in[2];
    const float* evalv = (const float*)d_in[3];
    const float* Wsum  = (const float*)d_in[4];
    const float* bsum  = (const float*)d_in[5];
    const float* Wprod = (const float*)d_in[6];
    const float* bprod = (const float*)d_in[7];
    float* out = (float*)d_out;

    const int D = 128;
    const int N = in_sizes[0] / D;
    const int E = in_sizes[1];
    const int L = in_sizes[5] / D;
    const size_t ND = (size_t)N * D;
    const int B = (N + 255) / 256;
    const int NB = (N + BROWS - 1) >> BSH;

    // workspace layout
    char* ws = (char*)d_ws;
    float* side    = (float*)ws;                 ws += ND * sizeof(float);
    float* ego_buf = (float*)ws;                 ws += ND * sizeof(float);
    int*   row_ptr  = (int*)ws;                  ws += (size_t)(N + 1) * sizeof(int);
    int*   row_fill = (int*)ws;                  ws += (size_t)N * sizeof(int);
    int*   blk_sums = (int*)ws;                  ws += (size_t)B * sizeof(int);
    ws = (char*)(((uintptr_t)ws + 15) & ~(uintptr_t)15);   // align for int2/vec
    int2*  csr_sv   = (int2*)ws;                 ws += (size_t)E * sizeof(int2);
    size_t csr_bytes = (size_t)(ws - (char*)d_ws);
    __bf16* WTsum  = (__bf16*)ws;                ws += (size_t)L * D * D * sizeof(__bf16);
    __bf16* WTprod = (__bf16*)ws;                ws += (size_t)L * D * D * sizeof(__bf16);
    __bf16* xbf    = (__bf16*)ws;                ws += ND * sizeof(__bf16);
    float*  nrm_buf = (float*)ws;                ws += (size_t)N * sizeof(float);
    size_t mfma_bytes = (size_t)(ws - (char*)d_ws);
    int* bucket_cnt  = (int*)ws;                 ws += (size_t)(NB + 1) * sizeof(int);
    int* bucket_ptr  = (int*)ws;                 ws += (size_t)(NB + 1) * sizeof(int);
    int* bucket_fill = (int*)ws;                 ws += (size_t)(NB + 1) * sizeof(int);
    size_t bucket_bytes = (size_t)(ws - (char*)d_ws);
    // staging (E x int4) aliases side+ego_buf (dead until first SpMM)
    int* stage = (int*)side;

    const bool use_csr    = (ws_size >= csr_bytes);
    const bool use_mfma   = (ws_size >= mfma_bytes);
    const bool use_bucket = use_csr && (ws_size >= bucket_bytes) && (NB <= NB_MAX) &&
                            ((size_t)E * 16 <= 2 * ND * sizeof(float));

    // out[0] = embeddings (+ bf16 copy for SpMM when mfma path active)
    if (use_mfma) {
        long long n4 = (long long)(ND / 4);
        emb_prep<<<(int)((n4 + 255) / 256), 256, 0, stream>>>(emb, out, xbf, n4);
        int total = L * D * D;
        wt_convert<<<(total + 255) / 256, 256, 0, stream>>>(
            Wsum, Wprod, WTsum, WTprod, total);
    } else {
        hipMemcpyAsync(out, emb, ND * sizeof(float), hipMemcpyDeviceToDevice, stream);
    }

    if (use_bucket) {
        const int nblk = (E + CHUNK - 1) / CHUNK;
        hipMemsetAsync(bucket_cnt, 0, (size_t)NB * sizeof(int), stream);
        bucket_count<<<nblk, 256, 0, stream>>>(edst, bucket_cnt, E, NB);
        bucket_scan<<<1, 256, 0, stream>>>(bucket_cnt, bucket_ptr, bucket_fill, NB, E);
        bucket_scatter<<<nblk, 256, 0, stream>>>(
            esrc, edst, evalv, bucket_fill, stage, NB, E);
        bucket_finalize<<<NB, 256, 0, stream>>>(
            stage, bucket_ptr, row_ptr, csr_sv, N, E);
    } else if (use_csr) {
        hipMemsetAsync(row_fill, 0, (size_t)N * sizeof(int), stream);
        hist_kernel<<<(E + 255) / 256, 256, 0, stream>>>(edst, row_fill, E);
        scan_blocks<<<B, 256, 0, stream>>>(row_fill, row_ptr, blk_sums, N);
        scan_carry<<<1, 256, 0, stream>>>(blk_sums, B);
        scan_add<<<B, 256, 0, stream>>>(row_ptr, blk_sums, row_fill, N, E);
        scatter_kernel<<<(E + 255) / 256, 256, 0, stream>>>(
            esrc, edst, evalv, row_fill, csr_sv, E);
    }

    const float* ego      = emb;       // fp32 ego source (or normalized w/ nrm)
    const float* nrm_prev = nullptr;   // per-row norm to reconstruct ego
    const float* spmm_in  = emb;       // fp32 spmm input (fallback paths)
    for (int l = 0; l < L; ++l) {
        if (use_csr) {
            if (use_mfma) {
                spmm_csr_bf16<<<(N + 7) / 8, 256, 0, stream>>>(
                    xbf, row_ptr, csr_sv, side, N);
            } else {
                spmm_csr_f32<<<(N + 7) / 8, 256, 0, stream>>>(
                    spmm_in, row_ptr, csr_sv, side, N);
            }
        } else {
            hipMemsetAsync(side, 0, ND * sizeof(float), stream);
            long long total  = (long long)E * 32;
            long long blocks = (total + 255) / 256;
            spmm_atomic<<<(int)blocks, 256, 0, stream>>>(spmm_in, esrc, edst, evalv,
                                                         side, total);
        }

        float* norm_out = out + (size_t)(l + 1) * ND;
        if (use_mfma) {
            const bool more = (l + 1 < L);
            __bf16* nbf  = more ? xbf : nullptr;      // next layer's SpMM input
            float*  nrmo = more ? nrm_buf : nullptr;  // next layer's ego scale
            fused_layer_mfma<<<(N + MROWS - 1) / MROWS, 512, 0, stream>>>(
                ego, nrm_prev, side,
                WTsum + (size_t)l * D * D, bsum + (size_t)l * D,
                WTprod + (size_t)l * D * D, bprod + (size_t)l * D,
                norm_out, nbf, nrmo, N);
            ego      = norm_out;
            nrm_prev = nrm_buf;
        } else {
            float* ego_out = (l + 1 < L) ? ego_buf : nullptr;
            fused_layer_f32<<<(N + ROWS - 1) / ROWS, 256, 0, stream>>>(
                ego, side,
                Wsum + (size_t)l * D * D, bsum + (size_t)l * D,
                Wprod + (size_t)l * D * D, bprod + (size_t)l * D,
                ego_out, norm_out, N);
            ego     = ego_buf;
            spmm_in = norm_out;
        }
    }
}